// Round 8
// baseline (450.997 us; speedup 1.0000x reference)
//
#include <hip/hip_runtime.h>
#include <stdint.h>

// ---------------------------------------------------------------------------
// Q_Attention: quantized ViT attention block, bit-faithful to the JAX/numpy ref.
// B=32, N=512, C=768, H=12, hd=64.  All GEMMs on i8 MFMA (int32 acc, exact).
// R8: R6 structure (barrier-free global-fragment GEMMs, XCD-affine swizzle,
// launch_bounds(256,4), NO register prefetch) + spill-free q/k epilogue:
// one seq sub-block at a time (live set acc + 32 floats < 128-reg budget).
// R7 lesson: register double-buffer spills (acc 64 + frags 64 > budget).
// ---------------------------------------------------------------------------

#define BB 32
#define NN 512
#define CC 768
#define HH 12
#define HD 64
#define M_ROWS (BB * NN)     // 16384
#define QKV_C (3 * CC)       // 2304
#define KTA ((size_t)M_ROWS * 64)   // x0q kt-slice stride
#define KTB ((size_t)QKV_C * 64)    // wq  kt-slice stride
#define KTP ((size_t)CC * 64)       // pwq kt-slice stride

typedef int v4i __attribute__((ext_vector_type(4)));
typedef int v16i __attribute__((ext_vector_type(16)));

__device__ __forceinline__ float fadd(float a, float b) { return __fadd_rn(a, b); }
__device__ __forceinline__ float fmul(float a, float b) { return __fmul_rn(a, b); }
__device__ __forceinline__ float fdiv(float a, float b) { return __fdiv_rn(a, b); }
__device__ __forceinline__ float fsub(float a, float b) { return __fsub_rn(a, b); }

// numpy pairwise_sum, n=96 (no remainder): 8 accumulators, then pairwise combine
__device__ float np_sum_96(const float* a) {
  float r[8];
#pragma unroll
  for (int j = 0; j < 8; j++) r[j] = a[j];
  for (int i = 8; i < 96; i += 8)
#pragma unroll
    for (int j = 0; j < 8; j++) r[j] = fadd(r[j], a[i + j]);
  return fadd(fadd(fadd(r[0], r[1]), fadd(r[2], r[3])),
              fadd(fadd(r[4], r[5]), fadd(r[6], r[7])));
}

// numpy pairwise mean of 12: 8-acc combine + 4 sequential remainder adds
__device__ float np_mean_12(const float* a) {
  float r[8];
#pragma unroll
  for (int j = 0; j < 8; j++) r[j] = a[j];
  float res = fadd(fadd(fadd(r[0], r[1]), fadd(r[2], r[3])),
                   fadd(fadd(r[4], r[5]), fadd(r[6], r[7])));
  res = fadd(res, a[8]);
  res = fadd(res, a[9]);
  res = fadd(res, a[10]);
  res = fadd(res, a[11]);
  return fdiv(res, 12.0f);
}

// ---------------------------------------------------------------------------
// prep: scalar means + folded LN quant params + integer qkv bias
// scal: [0]=a_in [1]=qact_m [2]=kact_m [3]=vact_m [4]=attnact_m [5]=pact_m
// qparams: [0:64]=qalpha [64:128]=qbias [128:192]=kalpha [192:256]=kbias
// ---------------------------------------------------------------------------
__global__ void prep_kernel(const float* __restrict__ qkv_act_alpha,
                            const float* __restrict__ proj_act_alpha,
                            const float* __restrict__ qact_alpha,
                            const float* __restrict__ kact_alpha,
                            const float* __restrict__ vact_alpha,
                            const float* __restrict__ attnact_alpha,
                            const float* __restrict__ normq_w,
                            const float* __restrict__ normq_b,
                            const float* __restrict__ normk_w,
                            const float* __restrict__ normk_b,
                            const float* __restrict__ qkv_bias,
                            const float* __restrict__ qkv_alpha,
                            float* __restrict__ scal,
                            float* __restrict__ qparams,
                            float* __restrict__ biasq) {
  __shared__ float s_scal[8];
  __shared__ float chunk[16];
  int tid = threadIdx.x;
  if (tid < 8) chunk[tid] = np_sum_96(qkv_act_alpha + 96 * tid);
  else if (tid < 16) chunk[tid] = np_sum_96(proj_act_alpha + 96 * (tid - 8));
  if (tid == 16) s_scal[1] = np_mean_12(qact_alpha);
  if (tid == 17) s_scal[2] = np_mean_12(kact_alpha);
  if (tid == 18) s_scal[3] = np_mean_12(vact_alpha);
  if (tid == 19) s_scal[4] = np_mean_12(attnact_alpha);
  __syncthreads();
  if (tid == 0) {
    float s0 = fadd(fadd(chunk[0], chunk[1]), fadd(chunk[2], chunk[3]));
    float s1 = fadd(fadd(chunk[4], chunk[5]), fadd(chunk[6], chunk[7]));
    s_scal[0] = fdiv(fadd(s0, s1), 768.0f);
    float p0 = fadd(fadd(chunk[8], chunk[9]), fadd(chunk[10], chunk[11]));
    float p1 = fadd(fadd(chunk[12], chunk[13]), fadd(chunk[14], chunk[15]));
    s_scal[5] = fdiv(fadd(p0, p1), 768.0f);
  }
  __syncthreads();
  if (tid < 6) scal[tid] = s_scal[tid];
  if (tid < 64) {
    qparams[tid]       = fdiv(s_scal[1], normq_w[tid]);    // act_a / nw
    qparams[64 + tid]  = fdiv(normq_b[tid], normq_w[tid]); // nb / nw
    qparams[128 + tid] = fdiv(s_scal[2], normk_w[tid]);
    qparams[192 + tid] = fdiv(normk_b[tid], normk_w[tid]);
  }
  float a_in = s_scal[0];
  for (int c = tid; c < QKV_C; c += blockDim.x)
    biasq[c] = truncf(fdiv(fdiv(qkv_bias[c], a_in), qkv_alpha[c]));
}

// x0_q = round(clip(x0 / a_in, -8, 7)) -> int8, K-TILED layout [12][16384][64]
__global__ void quant_x0_kernel(const float* __restrict__ x0,
                                const float* __restrict__ scal,
                                int8_t* __restrict__ x0q, int total4) {
  int i = blockIdx.x * blockDim.x + threadIdx.x;
  if (i >= total4) return;
  float a_in = scal[0];
  float4 v = ((const float4*)x0)[i];
  char4 o;
  o.x = (int8_t)rintf(fminf(fmaxf(fdiv(v.x, a_in), -8.f), 7.f));
  o.y = (int8_t)rintf(fminf(fmaxf(fdiv(v.y, a_in), -8.f), 7.f));
  o.z = (int8_t)rintf(fminf(fmaxf(fdiv(v.z, a_in), -8.f), 7.f));
  o.w = (int8_t)rintf(fminf(fmaxf(fdiv(v.w, a_in), -8.f), 7.f));
  int seq = i / 192;
  int kp = (i - seq * 192) * 4;
  *(char4*)(x0q + ((size_t)(kp >> 6) * M_ROWS + seq) * 64 + (kp & 63)) = o;
}

// row-wise 4-bit weight quant -> K-TILED layout [CC/64][rows][64]
__global__ void quant_w_kernel(const float* __restrict__ w,
                               const float* __restrict__ alpha,
                               int8_t* __restrict__ wq, int rows, int total) {
  int i = blockIdx.x * blockDim.x + threadIdx.x;
  if (i >= total) return;
  int row = i / CC;
  int k = i - row * CC;
  float t = fminf(fmaxf(fdiv(w[i], alpha[row]), -8.f), 7.f);
  wq[((size_t)(k >> 6) * rows + row) * 64 + (k & 63)] =
      (int8_t)rintf(t);
}

// ---------------------------------------------------------------------------
// GEMM1 (i8 MFMA 32x32x32): barrier-free.  Block = 256seq x 64ch; 4 waves
// each own 64x64 (2x2 of 32x32).  XCD-affine: xcd = L&7; rb = xcd + 8*(s/36);
// g = s%36 -> the 36 sharers of one A-slice run on one XCD (L2-resident).
// q/k: D = W*X^T; register LN one seq sub-block at a time (NO spill);
// v: D = X*W^T (swapped operands) dword-packed transpose.
// ---------------------------------------------------------------------------
__global__ __launch_bounds__(256, 4) void gemm_qkv_kernel(
    const int8_t* __restrict__ Aq, const int8_t* __restrict__ Wq,
    const float* __restrict__ biasq, const float* __restrict__ scal,
    const float* __restrict__ qkv_alpha, const float* __restrict__ qparams,
    int8_t* __restrict__ q2, int8_t* __restrict__ k2,
    int8_t* __restrict__ v2t) {
  __shared__ __align__(16) int8_t packT[4][5120];  // [wave][64 rows x 80]

  const int L = blockIdx.x;
  const int xcd = L & 7, s = L >> 3;
  const int rb = xcd + 8 * (s / 36);   // A row-slice 0..63 (XCD-resident)
  const int g = s % 36;                // column head 0..35
  const int tid = threadIdx.x;
  const int w = tid >> 6, lane = tid & 63;
  const int l31 = lane & 31, hi = lane >> 5;
  const int sec = g / HH, head = g % HH;
  const int col0 = g * 64;
  const int b_idx = rb >> 1, nbase = (rb & 1) * 256;
  const int w64 = w * 64;
  const size_t bh = (size_t)b_idx * HH + head;

  v16i acc[2][2];
#pragma unroll
  for (int i = 0; i < 2; i++)
#pragma unroll
    for (int j = 0; j < 2; j++) acc[i][j] = (v16i)(0);

  const int8_t* pa0 = Aq + ((size_t)(rb * 256 + w64 + l31)) * 64 + hi * 16;
  const int8_t* pa1 = pa0 + 32 * 64;
  const int8_t* pb0 = Wq + ((size_t)(col0 + l31)) * 64 + hi * 16;
  const int8_t* pb1 = pb0 + 32 * 64;

  if (sec < 2) {  // q/k: D = W * X^T
#pragma unroll
    for (int kt = 0; kt < 12; kt++) {
      v4i A0a = *(const v4i*)(pa0 + kt * KTA);
      v4i A1a = *(const v4i*)(pa1 + kt * KTA);
      v4i B0a = *(const v4i*)(pb0 + kt * KTB);
      v4i B1a = *(const v4i*)(pb1 + kt * KTB);
      v4i A0b = *(const v4i*)(pa0 + kt * KTA + 32);
      v4i A1b = *(const v4i*)(pa1 + kt * KTA + 32);
      v4i B0b = *(const v4i*)(pb0 + kt * KTB + 32);
      v4i B1b = *(const v4i*)(pb1 + kt * KTB + 32);
      acc[0][0] = __builtin_amdgcn_mfma_i32_32x32x32_i8(B0a, A0a, acc[0][0], 0, 0, 0);
      acc[0][1] = __builtin_amdgcn_mfma_i32_32x32x32_i8(B0a, A1a, acc[0][1], 0, 0, 0);
      acc[1][0] = __builtin_amdgcn_mfma_i32_32x32x32_i8(B1a, A0a, acc[1][0], 0, 0, 0);
      acc[1][1] = __builtin_amdgcn_mfma_i32_32x32x32_i8(B1a, A1a, acc[1][1], 0, 0, 0);
      acc[0][0] = __builtin_amdgcn_mfma_i32_32x32x32_i8(B0b, A0b, acc[0][0], 0, 0, 0);
      acc[0][1] = __builtin_amdgcn_mfma_i32_32x32x32_i8(B0b, A1b, acc[0][1], 0, 0, 0);
      acc[1][0] = __builtin_amdgcn_mfma_i32_32x32x32_i8(B1b, A0b, acc[1][0], 0, 0, 0);
      acc[1][1] = __builtin_amdgcn_mfma_i32_32x32x32_i8(B1b, A1b, acc[1][1], 0, 0, 0);
    }
    // ---- epilogue, one seq sub-block j at a time (live: acc + 32 floats) ----
    // acc[i][j][r]: ch = col0 + 32i + 8(r>>2) + 4hi + (r&3), seq = 32j + l31
    const float* ap = qparams + (sec == 0 ? 0 : 128);
    int8_t* dst = (sec == 0) ? q2 : k2;
#pragma unroll
    for (int j = 0; j < 2; j++) {
      float xsj[2][16];
#pragma unroll
      for (int i = 0; i < 2; i++)
#pragma unroll
        for (int b = 0; b < 4; b++) {
          int cg = col0 + 32 * i + 8 * b + 4 * hi;
          float4 bqv = *(const float4*)(biasq + cg);
          float4 alv = *(const float4*)(qkv_alpha + cg);
          const float* bqp = (const float*)&bqv;
          const float* alp = (const float*)&alv;
#pragma unroll
          for (int c = 0; c < 4; c++)
            xsj[i][4 * b + c] =
                fmul(fadd((float)acc[i][j][4 * b + c], bqp[c]), alp[c]);
        }
      // numpy-order stats: acc idx = ch&7 = 4hi+c (lane-local), t = ch>>3 = 4i+b
      float rc[4];
#pragma unroll
      for (int c = 0; c < 4; c++) rc[c] = xsj[0][c];
#pragma unroll
      for (int b = 1; b < 4; b++)
#pragma unroll
        for (int c = 0; c < 4; c++) rc[c] = fadd(rc[c], xsj[0][4 * b + c]);
#pragma unroll
      for (int b = 0; b < 4; b++)
#pragma unroll
        for (int c = 0; c < 4; c++) rc[c] = fadd(rc[c], xsj[1][4 * b + c]);
      float Ls = fadd(fadd(rc[0], rc[1]), fadd(rc[2], rc[3]));
      float Rs = __shfl_xor(Ls, 32, 64);
      float mn = fdiv(fadd(Ls, Rs), 64.0f);  // fadd commutative: lanes agree
      float vc[4];
#pragma unroll
      for (int c = 0; c < 4; c++) {
        float d = fsub(xsj[0][c], mn);
        vc[c] = fmul(d, d);
      }
#pragma unroll
      for (int b = 1; b < 4; b++)
#pragma unroll
        for (int c = 0; c < 4; c++) {
          float d = fsub(xsj[0][4 * b + c], mn);
          vc[c] = fadd(vc[c], fmul(d, d));
        }
#pragma unroll
      for (int b = 0; b < 4; b++)
#pragma unroll
        for (int c = 0; c < 4; c++) {
          float d = fsub(xsj[1][4 * b + c], mn);
          vc[c] = fadd(vc[c], fmul(d, d));
        }
      float Lv = fadd(fadd(vc[0], vc[1]), fadd(vc[2], vc[3]));
      float Rv = __shfl_xor(Lv, 32, 64);
      float var = fdiv(fadd(Lv, Rv), 63.0f);
      float den = fadd(__fsqrt_rn(var), 1e-5f);
#pragma unroll
      for (int i = 0; i < 2; i++)
#pragma unroll
        for (int b = 0; b < 4; b++) {
          int cin = 32 * i + 8 * b + 4 * hi;  // channel-in-head
          float4 a4 = *(const float4*)(ap + cin);
          float4 b4 = *(const float4*)(ap + 64 + cin);
          const float* a4p = (const float*)&a4;
          const float* b4p = (const float*)&b4;
          uint32_t pk = 0;
#pragma unroll
          for (int c = 0; c < 4; c++) {
            float xn = fdiv(fsub(xsj[i][4 * b + c], mn), den);
            float t = fdiv(fadd(xn, b4p[c]), a4p[c]);
            t = fminf(fmaxf(t, -4.f), 3.f);
            pk |= ((uint32_t)(uint8_t)(int8_t)rintf(t)) << (8 * c);
          }
          *(uint32_t*)&packT[w][(32 * j + l31) * 80 + cin] = pk;
        }
    }
    asm volatile("s_waitcnt lgkmcnt(0)" ::: "memory");
    size_t rowbase = bh * NN + nbase + w64;
#pragma unroll
    for (int c = 0; c < 4; c++) {
      int row = 16 * c + (lane >> 2), off = (lane & 3) * 16;
      int4 ov = *(const int4*)&packT[w][row * 80 + off];
      *(int4*)(dst + (rowbase + row) * 64 + off) = ov;
    }
  } else {  // v: D = X * W^T (row = seq -> dword-packed transpose)
#pragma unroll
    for (int kt = 0; kt < 12; kt++) {
      v4i A0a = *(const v4i*)(pa0 + kt * KTA);
      v4i A1a = *(const v4i*)(pa1 + kt * KTA);
      v4i B0a = *(const v4i*)(pb0 + kt * KTB);
      v4i B1a = *(const v4i*)(pb1 + kt * KTB);
      v4i A0b = *(const v4i*)(pa0 + kt * KTA + 32);
      v4i A1b = *(const v4i*)(pa1 + kt * KTA + 32);
      v4i B0b = *(const v4i*)(pb0 + kt * KTB + 32);
      v4i B1b = *(const v4i*)(pb1 + kt * KTB + 32);
      // acc[si][sj]: si = seq block, sj = ch block
      acc[0][0] = __builtin_amdgcn_mfma_i32_32x32x32_i8(A0a, B0a, acc[0][0], 0, 0, 0);
      acc[0][1] = __builtin_amdgcn_mfma_i32_32x32x32_i8(A0a, B1a, acc[0][1], 0, 0, 0);
      acc[1][0] = __builtin_amdgcn_mfma_i32_32x32x32_i8(A1a, B0a, acc[1][0], 0, 0, 0);
      acc[1][1] = __builtin_amdgcn_mfma_i32_32x32x32_i8(A1a, B1a, acc[1][1], 0, 0, 0);
      acc[0][0] = __builtin_amdgcn_mfma_i32_32x32x32_i8(A0b, B0b, acc[0][0], 0, 0, 0);
      acc[0][1] = __builtin_amdgcn_mfma_i32_32x32x32_i8(A0b, B1b, acc[0][1], 0, 0, 0);
      acc[1][0] = __builtin_amdgcn_mfma_i32_32x32x32_i8(A1b, B0b, acc[1][0], 0, 0, 0);
      acc[1][1] = __builtin_amdgcn_mfma_i32_32x32x32_i8(A1b, B1b, acc[1][1], 0, 0, 0);
    }
    // acc[si][sj][r]: seq = 32si + 8(r>>2) + 4hi + (r&3), ch(d) = 32sj + l31
    const float a_in = scal[0], vact = scal[3];
#pragma unroll
    for (int sj = 0; sj < 2; sj++) {
      int cg = col0 + 32 * sj + l31;
      float bq = biasq[cg];
      float va = fdiv(vact, fmul(a_in, qkv_alpha[cg]));
      int dloc = 32 * sj + l31;
#pragma unroll
      for (int si = 0; si < 2; si++)
#pragma unroll
        for (int b = 0; b < 4; b++) {
          uint32_t pk = 0;
#pragma unroll
          for (int c = 0; c < 4; c++) {
            float vint = fadd((float)acc[si][sj][4 * b + c], bq);
            float t = fminf(fmaxf(fdiv(vint, va), -4.f), 3.f);
            pk |= ((uint32_t)(uint8_t)(int8_t)rintf(t)) << (8 * c);
          }
          *(uint32_t*)&packT[w][dloc * 80 + 32 * si + 8 * b + 4 * hi] = pk;
        }
    }
    asm volatile("s_waitcnt lgkmcnt(0)" ::: "memory");
#pragma unroll
    for (int c = 0; c < 4; c++) {
      int row = 16 * c + (lane >> 2), off = (lane & 3) * 16;  // row = d
      int4 ov = *(const int4*)&packT[w][row * 80 + off];
      *(int4*)(v2t + (bh * HD + row) * NN + nbase + w64 + off) = ov;
    }
  }
}

// ---------------------------------------------------------------------------
// Attention (i8 MFMA), per (qtile64, b*h).  XCD-affine decode: the 8 qt-blocks
// of one (b,h) head run consecutively on one XCD -> K/V head L2-resident.
// ---------------------------------------------------------------------------
__global__ __launch_bounds__(256) void attn_kernel(
    const int8_t* __restrict__ q2, const int8_t* __restrict__ k2,
    const int8_t* __restrict__ v2t, const float* __restrict__ scal,
    int8_t* __restrict__ x1q) {
  __shared__ __align__(16) int8_t Qs[64][80];
  __shared__ __align__(16) int8_t Ks[64][80];
  __shared__ __align__(16) int8_t Vt[64][80];
  __shared__ __align__(16) int8_t At[64][80];

  const int L = blockIdx.x;
  const int xcd = L & 7, s = L >> 3;
  const int bh = xcd + 8 * (s >> 3);   // head 0..383 (XCD-resident K/V)
  const int qt = s & 7;                // q tile 0..7
  const int tid = threadIdx.x;
  const int w = tid >> 6, lane = tid & 63, quad = lane >> 4, c16 = lane & 15;
  const int sr = tid >> 2, scol = (tid & 3) << 4;
  const float attnm = scal[4];
  const float coef =
      fmul(1.4426950408889634f, fmul(fmul(0.125f, scal[1]), scal[2]));
  const float coef128 = fmul(coef, 128.f);
  const size_t base = (size_t)bh * NN * HD;

  *(int4*)&Qs[sr][scol] =
      *(const int4*)(q2 + base + (size_t)(qt * 64 + sr) * HD + scol);
  __syncthreads();
  v4i qf = *(const v4i*)&Qs[16 * w + c16][quad * 16];

  // ---- pass A: QK^T, m -> registers, row sums of 2^m ----
  uint32_t mpack[8][4];
  float Srow = 0.f;
  int4 kv = *(const int4*)(k2 + base + (size_t)sr * HD + scol);
#pragma unroll
  for (int kt = 0; kt < 8; kt++) {
    *(int4*)&Ks[sr][scol] = kv;
    __syncthreads();
    if (kt < 7)
      kv = *(const int4*)(k2 + base + (size_t)((kt + 1) * 64 + sr) * HD + scol);
    float psum = 0.f;
#pragma unroll
    for (int f = 0; f < 4; f++) {
      v4i kf = *(const v4i*)&Ks[16 * f + c16][quad * 16];
      v4i d2 = (v4i){0, 0, 0, 0};
      d2 = __builtin_amdgcn_mfma_i32_16x16x64_i8(kf, qf, d2, 0, 0, 0);
      uint32_t pk = 0;
#pragma unroll
      for (int r = 0; r < 4; r++) {
        float e = truncf(fmul(coef128, (float)d2[r]));
        int mi = (int)rintf(fmul(e, 0.0078125f));
        psum = fadd(psum, ldexpf(1.0f, mi));
        pk |= ((uint32_t)(uint8_t)(int8_t)mi) << (8 * r);
      }
      mpack[kt][f] = pk;
    }
    psum = fadd(psum, __shfl_xor(psum, 16, 64));
    psum = fadd(psum, __shfl_xor(psum, 32, 64));
    Srow = fadd(Srow, psum);
    __syncthreads();
  }
  const float u = fdiv(fdiv(1.0f, Srow), attnm);

  // ---- pass B: requantize from register m, AV ----
  v4i xacc[4];
#pragma unroll
  for (int s2 = 0; s2 < 4; s2++) xacc[s2] = (v4i){0, 0, 0, 0};

  int4 vv = *(const int4*)(v2t + ((size_t)bh * HD + sr) * NN + scol);
#pragma unroll
  for (int kt = 0; kt < 8; kt++) {
    *(int4*)&Vt[sr][scol] = vv;
    __syncthreads();
    if (kt < 7)
      vv = *(const int4*)(v2t + ((size_t)bh * HD + sr) * NN + (kt + 1) * 64 +
                          scol);
#pragma unroll
    for (int f = 0; f < 4; f++) {
      uint32_t pk = mpack[kt][f];
      uint32_t wpk = 0;
#pragma unroll
      for (int r = 0; r < 4; r++) {
        int mi = (int)(int8_t)(pk >> (8 * r));
        float t = fminf(ldexpf(u, mi), 7.f);
        wpk |= ((uint32_t)(uint8_t)(int8_t)rintf(t)) << (8 * r);
      }
      *(uint32_t*)&At[16 * w + c16][16 * f + 4 * quad] = wpk;
    }
    asm volatile("s_waitcnt lgkmcnt(0)" ::: "memory");
    v4i af = *(const v4i*)&At[16 * w + c16][quad * 16];
#pragma unroll
    for (int s2 = 0; s2 < 4; s2++) {
      v4i vf = *(const v4i*)&Vt[16 * s2 + c16][quad * 16];
      xacc[s2] = __builtin_amdgcn_mfma_i32_16x16x64_i8(vf, af, xacc[s2], 0, 0, 0);
    }
    __syncthreads();
  }

  const float pa = fdiv(scal[5], fmul(attnm, scal[3]));
#pragma unroll
  for (int s2 = 0; s2 < 4; s2++) {
    uint32_t pack = 0;
#pragma unroll
    for (int r = 0; r < 4; r++) {
      float t = fminf(fmaxf(fdiv((float)xacc[s2][r], pa), -4.f), 3.f);
      pack |= ((uint32_t)(uint8_t)(int8_t)rintf(t)) << (8 * r);
    }
    *(uint32_t*)&Ks[16 * w + c16][16 * s2 + 4 * quad] = pack;
  }
  __syncthreads();
  int4 ov = *(const int4*)&Ks[sr][scol];
  *(int4*)(x1q + ((size_t)bh * NN + qt * 64 + sr) * HD + scol) = ov;
}

// ---------------------------------------------------------------------------
// GEMM2 (i8 MFMA 32x32x32): barrier-free, LDS-free (R6 form).  XCD-affine:
// 12 column-blocks sharing one x1q row-slice run on one XCD.
// ---------------------------------------------------------------------------
__global__ __launch_bounds__(256, 4) void gemm_proj_kernel(
    const int8_t* __restrict__ x1q, const int8_t* __restrict__ Wq,
    const float* __restrict__ proj_alpha, const float* __restrict__ proj_bias,
    const float* __restrict__ scal, float* __restrict__ out) {
  const int L = blockIdx.x;
  const int xcd = L & 7, s = L >> 3;
  const int rb = xcd + 8 * (s / 12);   // row-slice 0..63 (XCD-resident)
  const int g = s % 12;                // column block 0..11
  const int tid = threadIdx.x;
  const int w = tid >> 6, lane = tid & 63;
  const int l31 = lane & 31, hi = lane >> 5;
  const int col0 = g * 64;
  const int b_idx = rb >> 1, nbase = (rb & 1) * 256;
  const int w64 = w * 64;

  v16i acc[2][2];
#pragma unroll
  for (int i = 0; i < 2; i++)
#pragma unroll
    for (int j = 0; j < 2; j++) acc[i][j] = (v16i)(0);

  const int8_t* pa0 =
      x1q + ((size_t)b_idx * HH * NN + nbase + w64 + l31) * 64 + hi * 16;
  const int8_t* pa1 = pa0 + 32 * 64;
  const int8_t* pb0 = Wq + ((size_t)(col0 + l31)) * 64 + hi * 16;
  const int8_t* pb1 = pb0 + 32 * 64;
  const size_t KTX = (size_t)NN * 64;  // head stride in x1q

#pragma unroll
  for (int kt = 0; kt < 12; kt++) {
    v4i A0a = *(const v4i*)(pa0 + kt * KTX);
    v4i A1a = *(const v4i*)(pa1 + kt * KTX);
    v4i B0a = *(const v4i*)(pb0 + kt * KTP);
    v4i B1a = *(const v4i*)(pb1 + kt * KTP);
    v4i A0b = *(const v4i*)(pa0 + kt * KTX + 32);
    v4i A1b = *(const v4i*)(pa1 + kt * KTX + 32);
    v4i B0b = *(const v4i*)(pb0 + kt * KTP + 32);
    v4i B1b = *(const v4i*)(pb1 + kt * KTP + 32);
    acc[0][0] = __builtin_amdgcn_mfma_i32_32x32x32_i8(B0a, A0a, acc[0][0], 0, 0, 0);
    acc[0][1] = __builtin_amdgcn_mfma_i32_32x32x32_i8(B0a, A1a, acc[0][1], 0, 0, 0);
    acc[1][0] = __builtin_amdgcn_mfma_i32_32x32x32_i8(B1a, A0a, acc[1][0], 0, 0, 0);
    acc[1][1] = __builtin_amdgcn_mfma_i32_32x32x32_i8(B1a, A1a, acc[1][1], 0, 0, 0);
    acc[0][0] = __builtin_amdgcn_mfma_i32_32x32x32_i8(B0b, A0b, acc[0][0], 0, 0, 0);
    acc[0][1] = __builtin_amdgcn_mfma_i32_32x32x32_i8(B0b, A1b, acc[0][1], 0, 0, 0);
    acc[1][0] = __builtin_amdgcn_mfma_i32_32x32x32_i8(B1b, A0b, acc[1][0], 0, 0, 0);
    acc[1][1] = __builtin_amdgcn_mfma_i32_32x32x32_i8(B1b, A1b, acc[1][1], 0, 0, 0);
  }

  const float pact = scal[5];
  const int seqbase = rb * 256 + w64;
#pragma unroll
  for (int i = 0; i < 2; i++)
#pragma unroll
    for (int b = 0; b < 4; b++) {
      int colb = col0 + 32 * i + 8 * b + 4 * hi;
      float4 al = *(const float4*)(proj_alpha + colb);
      float4 bi = *(const float4*)(proj_bias + colb);
      const float* alp = (const float*)&al;
      const float* bip = (const float*)&bi;
#pragma unroll
      for (int j = 0; j < 2; j++) {
        int m = seqbase + 32 * j + l31;
        float4 o;
        float* op = (float*)&o;
#pragma unroll
        for (int c = 0; c < 4; c++)
          op[c] = fadd(fmul(fmul((float)acc[i][j][4 * b + c], alp[c]), pact),
                       bip[c]);
        *(float4*)(out + (size_t)m * CC + colb) = o;
      }
    }
}

extern "C" void kernel_launch(void* const* d_in, const int* in_sizes, int n_in,
                              void* d_out, int out_size, void* d_ws,
                              size_t ws_size, hipStream_t stream) {
  const float* x0 = (const float*)d_in[0];
  const float* qkv_w = (const float*)d_in[1];
  const float* qkv_alpha = (const float*)d_in[2];
  const float* qkv_bias = (const float*)d_in[3];
  const float* qkv_act_alpha = (const float*)d_in[4];
  const float* proj_w = (const float*)d_in[5];
  const float* proj_alpha = (const float*)d_in[6];
  const float* proj_bias = (const float*)d_in[7];
  const float* proj_act_alpha = (const float*)d_in[8];
  const float* normq_w = (const float*)d_in[9];
  const float* normq_b = (const float*)d_in[10];
  const float* normk_w = (const float*)d_in[11];
  const float* normk_b = (const float*)d_in[12];
  const float* qact_alpha = (const float*)d_in[13];
  const float* kact_alpha = (const float*)d_in[14];
  const float* vact_alpha = (const float*)d_in[15];
  const float* attnact_alpha = (const float*)d_in[16];

  char* ws = (char*)d_ws;
  size_t off = 0;
  auto alloc = [&](size_t bytes) -> char* {
    char* p = ws + off;
    off += (bytes + 255) & ~(size_t)255;
    return p;
  };
  float* scal = (float*)alloc(64 * 4);
  float* qparams = (float*)alloc(256 * 4);
  float* biasq = (float*)alloc(QKV_C * 4);
  int8_t* x0q = (int8_t*)alloc((size_t)M_ROWS * CC);   // tiled [12][16384][64]
  int8_t* wq = (int8_t*)alloc((size_t)QKV_C * CC);     // tiled [12][2304][64]
  int8_t* pwq = (int8_t*)alloc((size_t)CC * CC);       // tiled [12][768][64]
  int8_t* q2 = (int8_t*)alloc((size_t)BB * HH * NN * HD);
  int8_t* k2 = (int8_t*)alloc((size_t)BB * HH * NN * HD);
  int8_t* v2t = (int8_t*)alloc((size_t)BB * HH * NN * HD);
  int8_t* x1q = (int8_t*)alloc((size_t)M_ROWS * CC);

  prep_kernel<<<1, 256, 0, stream>>>(qkv_act_alpha, proj_act_alpha, qact_alpha,
                                     kact_alpha, vact_alpha, attnact_alpha,
                                     normq_w, normq_b, normk_w, normk_b,
                                     qkv_bias, qkv_alpha, scal, qparams, biasq);

  int total4 = M_ROWS * CC / 4;
  quant_x0_kernel<<<(total4 + 255) / 256, 256, 0, stream>>>(x0, scal, x0q,
                                                            total4);
  quant_w_kernel<<<(QKV_C * CC + 255) / 256, 256, 0, stream>>>(
      qkv_w, qkv_alpha, wq, QKV_C, QKV_C * CC);
  quant_w_kernel<<<(CC * CC + 255) / 256, 256, 0, stream>>>(
      proj_w, proj_alpha, pwq, CC, CC * CC);

  gemm_qkv_kernel<<<QKV_C / 64 * (M_ROWS / 256), 256, 0, stream>>>(
      x0q, wq, biasq, scal, qkv_alpha, qparams, q2, k2, v2t);

  attn_kernel<<<(NN / 64) * (BB * HH), 256, 0, stream>>>(q2, k2, v2t, scal,
                                                         x1q);

  gemm_proj_kernel<<<(CC / 64) * (M_ROWS / 256), 256, 0, stream>>>(
      x1q, pwq, proj_alpha, proj_bias, scal, (float*)d_out);
}

// Round 9
// 388.494 us; speedup vs baseline: 1.1609x; 1.1609x over previous
//
#include <hip/hip_runtime.h>
#include <stdint.h>

// ---------------------------------------------------------------------------
// Q_Attention: quantized ViT attention block, bit-faithful to the JAX/numpy ref.
// B=32, N=512, C=768, H=12, hd=64.  All GEMMs on i8 MFMA (int32 acc, exact).
// R9: spill-free by construction.  Lesson R5-R8: compiler splits the unified
// file 64 AGPR (acc) + 64 arch VGPR; any epilogue array overflows the VGPR
// half -> 150-360 MB scratch traffic.  Fix: (a) LN epilogue RECOMPUTES
// x=(acc+bq)*alpha in each of 3 passes (sum/var/quant) straight from AGPRs —
// no xs array; (b) opq() empty-asm barriers defeat CSE so the recompute can't
// be "optimized" back into 32 live floats; (c) K-loop = 2 half-K steps of
// 4 loads + 4 MFMAs, #pragma unroll 1 (no 12x load hoisting).
// XCD-affine swizzle kept.  Arithmetic order identical to verified rounds.
// ---------------------------------------------------------------------------

#define BB 32
#define NN 512
#define CC 768
#define HH 12
#define HD 64
#define M_ROWS (BB * NN)     // 16384
#define QKV_C (3 * CC)       // 2304
#define KTA ((size_t)M_ROWS * 64)   // x0q kt-slice stride
#define KTB ((size_t)QKV_C * 64)    // wq  kt-slice stride
#define KTP ((size_t)CC * 64)       // pwq kt-slice stride

typedef int v4i __attribute__((ext_vector_type(4)));
typedef int v16i __attribute__((ext_vector_type(16)));

__device__ __forceinline__ float fadd(float a, float b) { return __fadd_rn(a, b); }
__device__ __forceinline__ float fmul(float a, float b) { return __fmul_rn(a, b); }
__device__ __forceinline__ float fdiv(float a, float b) { return __fdiv_rn(a, b); }
__device__ __forceinline__ float fsub(float a, float b) { return __fsub_rn(a, b); }
// opaque value barrier: blocks CSE/rematerialization across epilogue passes
__device__ __forceinline__ int opq(int v) { asm("" : "+v"(v)); return v; }

// numpy pairwise_sum, n=96 (no remainder): 8 accumulators, then pairwise combine
__device__ float np_sum_96(const float* a) {
  float r[8];
#pragma unroll
  for (int j = 0; j < 8; j++) r[j] = a[j];
  for (int i = 8; i < 96; i += 8)
#pragma unroll
    for (int j = 0; j < 8; j++) r[j] = fadd(r[j], a[i + j]);
  return fadd(fadd(fadd(r[0], r[1]), fadd(r[2], r[3])),
              fadd(fadd(r[4], r[5]), fadd(r[6], r[7])));
}

// numpy pairwise mean of 12: 8-acc combine + 4 sequential remainder adds
__device__ float np_mean_12(const float* a) {
  float r[8];
#pragma unroll
  for (int j = 0; j < 8; j++) r[j] = a[j];
  float res = fadd(fadd(fadd(r[0], r[1]), fadd(r[2], r[3])),
                   fadd(fadd(r[4], r[5]), fadd(r[6], r[7])));
  res = fadd(res, a[8]);
  res = fadd(res, a[9]);
  res = fadd(res, a[10]);
  res = fadd(res, a[11]);
  return fdiv(res, 12.0f);
}

// ---------------------------------------------------------------------------
// prep: scalar means + folded LN quant params + integer qkv bias
// scal: [0]=a_in [1]=qact_m [2]=kact_m [3]=vact_m [4]=attnact_m [5]=pact_m
// qparams: [0:64]=qalpha [64:128]=qbias [128:192]=kalpha [192:256]=kbias
// ---------------------------------------------------------------------------
__global__ void prep_kernel(const float* __restrict__ qkv_act_alpha,
                            const float* __restrict__ proj_act_alpha,
                            const float* __restrict__ qact_alpha,
                            const float* __restrict__ kact_alpha,
                            const float* __restrict__ vact_alpha,
                            const float* __restrict__ attnact_alpha,
                            const float* __restrict__ normq_w,
                            const float* __restrict__ normq_b,
                            const float* __restrict__ normk_w,
                            const float* __restrict__ normk_b,
                            const float* __restrict__ qkv_bias,
                            const float* __restrict__ qkv_alpha,
                            float* __restrict__ scal,
                            float* __restrict__ qparams,
                            float* __restrict__ biasq) {
  __shared__ float s_scal[8];
  __shared__ float chunk[16];
  int tid = threadIdx.x;
  if (tid < 8) chunk[tid] = np_sum_96(qkv_act_alpha + 96 * tid);
  else if (tid < 16) chunk[tid] = np_sum_96(proj_act_alpha + 96 * (tid - 8));
  if (tid == 16) s_scal[1] = np_mean_12(qact_alpha);
  if (tid == 17) s_scal[2] = np_mean_12(kact_alpha);
  if (tid == 18) s_scal[3] = np_mean_12(vact_alpha);
  if (tid == 19) s_scal[4] = np_mean_12(attnact_alpha);
  __syncthreads();
  if (tid == 0) {
    float s0 = fadd(fadd(chunk[0], chunk[1]), fadd(chunk[2], chunk[3]));
    float s1 = fadd(fadd(chunk[4], chunk[5]), fadd(chunk[6], chunk[7]));
    s_scal[0] = fdiv(fadd(s0, s1), 768.0f);
    float p0 = fadd(fadd(chunk[8], chunk[9]), fadd(chunk[10], chunk[11]));
    float p1 = fadd(fadd(chunk[12], chunk[13]), fadd(chunk[14], chunk[15]));
    s_scal[5] = fdiv(fadd(p0, p1), 768.0f);
  }
  __syncthreads();
  if (tid < 6) scal[tid] = s_scal[tid];
  if (tid < 64) {
    qparams[tid]       = fdiv(s_scal[1], normq_w[tid]);    // act_a / nw
    qparams[64 + tid]  = fdiv(normq_b[tid], normq_w[tid]); // nb / nw
    qparams[128 + tid] = fdiv(s_scal[2], normk_w[tid]);
    qparams[192 + tid] = fdiv(normk_b[tid], normk_w[tid]);
  }
  float a_in = s_scal[0];
  for (int c = tid; c < QKV_C; c += blockDim.x)
    biasq[c] = truncf(fdiv(fdiv(qkv_bias[c], a_in), qkv_alpha[c]));
}

// x0_q = round(clip(x0 / a_in, -8, 7)) -> int8, K-TILED layout [12][16384][64]
__global__ void quant_x0_kernel(const float* __restrict__ x0,
                                const float* __restrict__ scal,
                                int8_t* __restrict__ x0q, int total4) {
  int i = blockIdx.x * blockDim.x + threadIdx.x;
  if (i >= total4) return;
  float a_in = scal[0];
  float4 v = ((const float4*)x0)[i];
  char4 o;
  o.x = (int8_t)rintf(fminf(fmaxf(fdiv(v.x, a_in), -8.f), 7.f));
  o.y = (int8_t)rintf(fminf(fmaxf(fdiv(v.y, a_in), -8.f), 7.f));
  o.z = (int8_t)rintf(fminf(fmaxf(fdiv(v.z, a_in), -8.f), 7.f));
  o.w = (int8_t)rintf(fminf(fmaxf(fdiv(v.w, a_in), -8.f), 7.f));
  int seq = i / 192;
  int kp = (i - seq * 192) * 4;
  *(char4*)(x0q + ((size_t)(kp >> 6) * M_ROWS + seq) * 64 + (kp & 63)) = o;
}

// row-wise 4-bit weight quant -> K-TILED layout [CC/64][rows][64]
__global__ void quant_w_kernel(const float* __restrict__ w,
                               const float* __restrict__ alpha,
                               int8_t* __restrict__ wq, int rows, int total) {
  int i = blockIdx.x * blockDim.x + threadIdx.x;
  if (i >= total) return;
  int row = i / CC;
  int k = i - row * CC;
  float t = fminf(fmaxf(fdiv(w[i], alpha[row]), -8.f), 7.f);
  wq[((size_t)(k >> 6) * rows + row) * 64 + (k & 63)] =
      (int8_t)rintf(t);
}

// ---------------------------------------------------------------------------
// GEMM1 (i8 MFMA 32x32x32): barrier-free.  Block = 256seq x 64ch; 4 waves
// each own 64x64 (2x2 of 32x32).  XCD-affine: xcd = L&7; rb = xcd + 8*(s/36);
// g = s%36 -> the 36 sharers of one A-slice run on one XCD (L2-resident).
// K-loop: #pragma unroll 1, two K=32 half-steps of 4 loads + 4 MFMAs.
// q/k: D = W*X^T; LN epilogue recomputes x from AGPR acc in 3 passes (opq
// barriers block CSE) -> ~15 live VGPRs, no scratch.
// v: D = X*W^T dword-packed transpose.
// ---------------------------------------------------------------------------
__global__ __launch_bounds__(256, 4) void gemm_qkv_kernel(
    const int8_t* __restrict__ Aq, const int8_t* __restrict__ Wq,
    const float* __restrict__ biasq, const float* __restrict__ scal,
    const float* __restrict__ qkv_alpha, const float* __restrict__ qparams,
    int8_t* __restrict__ q2, int8_t* __restrict__ k2,
    int8_t* __restrict__ v2t) {
  __shared__ __align__(16) int8_t packT[4][5120];  // [wave][64 rows x 80]

  const int L = blockIdx.x;
  const int xcd = L & 7, s = L >> 3;
  const int rb = xcd + 8 * (s / 36);   // A row-slice 0..63 (XCD-resident)
  const int g = s % 36;                // column head 0..35
  const int tid = threadIdx.x;
  const int w = tid >> 6, lane = tid & 63;
  const int l31 = lane & 31, hi = lane >> 5;
  const int sec = g / HH, head = g % HH;
  const int col0 = g * 64;
  const int b_idx = rb >> 1, nbase = (rb & 1) * 256;
  const int w64 = w * 64;
  const size_t bh = (size_t)b_idx * HH + head;

  v16i acc[2][2];
#pragma unroll
  for (int i = 0; i < 2; i++)
#pragma unroll
    for (int j = 0; j < 2; j++) acc[i][j] = (v16i)(0);

  const int8_t* pa0 = Aq + ((size_t)(rb * 256 + w64 + l31)) * 64 + hi * 16;
  const int8_t* pa1 = pa0 + 32 * 64;
  const int8_t* pb0 = Wq + ((size_t)(col0 + l31)) * 64 + hi * 16;
  const int8_t* pb1 = pb0 + 32 * 64;

  if (sec < 2) {  // q/k: D = W * X^T
#pragma unroll 1
    for (int kt = 0; kt < 12; kt++) {
      {
        v4i A0 = *(const v4i*)(pa0 + kt * KTA);
        v4i A1 = *(const v4i*)(pa1 + kt * KTA);
        v4i B0 = *(const v4i*)(pb0 + kt * KTB);
        v4i B1 = *(const v4i*)(pb1 + kt * KTB);
        acc[0][0] = __builtin_amdgcn_mfma_i32_32x32x32_i8(B0, A0, acc[0][0], 0, 0, 0);
        acc[0][1] = __builtin_amdgcn_mfma_i32_32x32x32_i8(B0, A1, acc[0][1], 0, 0, 0);
        acc[1][0] = __builtin_amdgcn_mfma_i32_32x32x32_i8(B1, A0, acc[1][0], 0, 0, 0);
        acc[1][1] = __builtin_amdgcn_mfma_i32_32x32x32_i8(B1, A1, acc[1][1], 0, 0, 0);
      }
      {
        v4i A0 = *(const v4i*)(pa0 + kt * KTA + 32);
        v4i A1 = *(const v4i*)(pa1 + kt * KTA + 32);
        v4i B0 = *(const v4i*)(pb0 + kt * KTB + 32);
        v4i B1 = *(const v4i*)(pb1 + kt * KTB + 32);
        acc[0][0] = __builtin_amdgcn_mfma_i32_32x32x32_i8(B0, A0, acc[0][0], 0, 0, 0);
        acc[0][1] = __builtin_amdgcn_mfma_i32_32x32x32_i8(B0, A1, acc[0][1], 0, 0, 0);
        acc[1][0] = __builtin_amdgcn_mfma_i32_32x32x32_i8(B1, A0, acc[1][0], 0, 0, 0);
        acc[1][1] = __builtin_amdgcn_mfma_i32_32x32x32_i8(B1, A1, acc[1][1], 0, 0, 0);
      }
    }
    // ---- LN epilogue: 3 recompute passes per seq sub-block j (no xs array) --
    // acc[i][j][r]: ch = col0 + 32i + 8(r>>2) + 4hi + (r&3), seq = 32j + l31
    const float* ap = qparams + (sec == 0 ? 0 : 128);
    int8_t* dst = (sec == 0) ? q2 : k2;
#pragma unroll
    for (int j = 0; j < 2; j++) {
      // pass S: mean (numpy 8-acc order: acc idx = ch&7 = 4hi+c, t = 4i+b)
      float rc[4];
#pragma unroll
      for (int i = 0; i < 2; i++)
#pragma unroll
        for (int b = 0; b < 4; b++) {
          int cg = opq(col0 + 32 * i + 8 * b + 4 * hi);
          float4 bqv = *(const float4*)(biasq + cg);
          float4 alv = *(const float4*)(qkv_alpha + cg);
          const float* bqp = (const float*)&bqv;
          const float* alp = (const float*)&alv;
#pragma unroll
          for (int c = 0; c < 4; c++) {
            float x = fmul(fadd((float)opq(acc[i][j][4 * b + c]), bqp[c]), alp[c]);
            rc[c] = (i == 0 && b == 0) ? x : fadd(rc[c], x);
          }
        }
      float Ls = fadd(fadd(rc[0], rc[1]), fadd(rc[2], rc[3]));
      float Rs = __shfl_xor(Ls, 32, 64);
      float mn = fdiv(fadd(Ls, Rs), 64.0f);  // fadd commutative: lanes agree
      // pass V: variance
      float vc[4];
#pragma unroll
      for (int i = 0; i < 2; i++)
#pragma unroll
        for (int b = 0; b < 4; b++) {
          int cg = opq(col0 + 32 * i + 8 * b + 4 * hi);
          float4 bqv = *(const float4*)(biasq + cg);
          float4 alv = *(const float4*)(qkv_alpha + cg);
          const float* bqp = (const float*)&bqv;
          const float* alp = (const float*)&alv;
#pragma unroll
          for (int c = 0; c < 4; c++) {
            float x = fmul(fadd((float)opq(acc[i][j][4 * b + c]), bqp[c]), alp[c]);
            float d = fsub(x, mn);
            float sq = fmul(d, d);
            vc[c] = (i == 0 && b == 0) ? sq : fadd(vc[c], sq);
          }
        }
      float Lv = fadd(fadd(vc[0], vc[1]), fadd(vc[2], vc[3]));
      float Rv = __shfl_xor(Lv, 32, 64);
      float var = fdiv(fadd(Lv, Rv), 63.0f);
      float den = fadd(__fsqrt_rn(var), 1e-5f);
      // pass Q: quantize + pack
#pragma unroll
      for (int i = 0; i < 2; i++)
#pragma unroll
        for (int b = 0; b < 4; b++) {
          int cin = 32 * i + 8 * b + 4 * hi;  // channel-in-head
          int cg = opq(col0 + cin);
          float4 bqv = *(const float4*)(biasq + cg);
          float4 alv = *(const float4*)(qkv_alpha + cg);
          float4 a4 = *(const float4*)(ap + cin);
          float4 b4 = *(const float4*)(ap + 64 + cin);
          const float* bqp = (const float*)&bqv;
          const float* alp = (const float*)&alv;
          const float* a4p = (const float*)&a4;
          const float* b4p = (const float*)&b4;
          uint32_t pk = 0;
#pragma unroll
          for (int c = 0; c < 4; c++) {
            float x = fmul(fadd((float)opq(acc[i][j][4 * b + c]), bqp[c]), alp[c]);
            float xn = fdiv(fsub(x, mn), den);
            float t = fdiv(fadd(xn, b4p[c]), a4p[c]);
            t = fminf(fmaxf(t, -4.f), 3.f);
            pk |= ((uint32_t)(uint8_t)(int8_t)rintf(t)) << (8 * c);
          }
          *(uint32_t*)&packT[w][(32 * j + l31) * 80 + cin] = pk;
        }
    }
    asm volatile("s_waitcnt lgkmcnt(0)" ::: "memory");
    size_t rowbase = bh * NN + nbase + w64;
#pragma unroll
    for (int c = 0; c < 4; c++) {
      int row = 16 * c + (lane >> 2), off = (lane & 3) * 16;
      int4 ov = *(const int4*)&packT[w][row * 80 + off];
      *(int4*)(dst + (rowbase + row) * 64 + off) = ov;
    }
  } else {  // v: D = X * W^T (row = seq -> dword-packed transpose)
#pragma unroll 1
    for (int kt = 0; kt < 12; kt++) {
      {
        v4i A0 = *(const v4i*)(pa0 + kt * KTA);
        v4i A1 = *(const v4i*)(pa1 + kt * KTA);
        v4i B0 = *(const v4i*)(pb0 + kt * KTB);
        v4i B1 = *(const v4i*)(pb1 + kt * KTB);
        acc[0][0] = __builtin_amdgcn_mfma_i32_32x32x32_i8(A0, B0, acc[0][0], 0, 0, 0);
        acc[0][1] = __builtin_amdgcn_mfma_i32_32x32x32_i8(A0, B1, acc[0][1], 0, 0, 0);
        acc[1][0] = __builtin_amdgcn_mfma_i32_32x32x32_i8(A1, B0, acc[1][0], 0, 0, 0);
        acc[1][1] = __builtin_amdgcn_mfma_i32_32x32x32_i8(A1, B1, acc[1][1], 0, 0, 0);
      }
      {
        v4i A0 = *(const v4i*)(pa0 + kt * KTA + 32);
        v4i A1 = *(const v4i*)(pa1 + kt * KTA + 32);
        v4i B0 = *(const v4i*)(pb0 + kt * KTB + 32);
        v4i B1 = *(const v4i*)(pb1 + kt * KTB + 32);
        acc[0][0] = __builtin_amdgcn_mfma_i32_32x32x32_i8(A0, B0, acc[0][0], 0, 0, 0);
        acc[0][1] = __builtin_amdgcn_mfma_i32_32x32x32_i8(A0, B1, acc[0][1], 0, 0, 0);
        acc[1][0] = __builtin_amdgcn_mfma_i32_32x32x32_i8(A1, B0, acc[1][0], 0, 0, 0);
        acc[1][1] = __builtin_amdgcn_mfma_i32_32x32x32_i8(A1, B1, acc[1][1], 0, 0, 0);
      }
    }
    // acc[si][sj][r]: seq = 32si + 8(r>>2) + 4hi + (r&3), ch(d) = 32sj + l31
    const float a_in = scal[0], vact = scal[3];
#pragma unroll
    for (int sj = 0; sj < 2; sj++) {
      int cg = col0 + 32 * sj + l31;
      float bq = biasq[cg];
      float va = fdiv(vact, fmul(a_in, qkv_alpha[cg]));
      int dloc = 32 * sj + l31;
#pragma unroll
      for (int si = 0; si < 2; si++)
#pragma unroll
        for (int b = 0; b < 4; b++) {
          uint32_t pk = 0;
#pragma unroll
          for (int c = 0; c < 4; c++) {
            float vint = fadd((float)acc[si][sj][4 * b + c], bq);
            float t = fminf(fmaxf(fdiv(vint, va), -4.f), 3.f);
            pk |= ((uint32_t)(uint8_t)(int8_t)rintf(t)) << (8 * c);
          }
          *(uint32_t*)&packT[w][dloc * 80 + 32 * si + 8 * b + 4 * hi] = pk;
        }
    }
    asm volatile("s_waitcnt lgkmcnt(0)" ::: "memory");
#pragma unroll
    for (int c = 0; c < 4; c++) {
      int row = 16 * c + (lane >> 2), off = (lane & 3) * 16;  // row = d
      int4 ov = *(const int4*)&packT[w][row * 80 + off];
      *(int4*)(v2t + (bh * HD + row) * NN + nbase + w64 + off) = ov;
    }
  }
}

// ---------------------------------------------------------------------------
// Attention (i8 MFMA), per (qtile64, b*h).  XCD-affine decode: the 8 qt-blocks
// of one (b,h) head run consecutively on one XCD -> K/V head L2-resident.
// ---------------------------------------------------------------------------
__global__ __launch_bounds__(256) void attn_kernel(
    const int8_t* __restrict__ q2, const int8_t* __restrict__ k2,
    const int8_t* __restrict__ v2t, const float* __restrict__ scal,
    int8_t* __restrict__ x1q) {
  __shared__ __align__(16) int8_t Qs[64][80];
  __shared__ __align__(16) int8_t Ks[64][80];
  __shared__ __align__(16) int8_t Vt[64][80];
  __shared__ __align__(16) int8_t At[64][80];

  const int L = blockIdx.x;
  const int xcd = L & 7, s = L >> 3;
  const int bh = xcd + 8 * (s >> 3);   // head 0..383 (XCD-resident K/V)
  const int qt = s & 7;                // q tile 0..7
  const int tid = threadIdx.x;
  const int w = tid >> 6, lane = tid & 63, quad = lane >> 4, c16 = lane & 15;
  const int sr = tid >> 2, scol = (tid & 3) << 4;
  const float attnm = scal[4];
  const float coef =
      fmul(1.4426950408889634f, fmul(fmul(0.125f, scal[1]), scal[2]));
  const float coef128 = fmul(coef, 128.f);
  const size_t base = (size_t)bh * NN * HD;

  *(int4*)&Qs[sr][scol] =
      *(const int4*)(q2 + base + (size_t)(qt * 64 + sr) * HD + scol);
  __syncthreads();
  v4i qf = *(const v4i*)&Qs[16 * w + c16][quad * 16];

  // ---- pass A: QK^T, m -> registers, row sums of 2^m ----
  uint32_t mpack[8][4];
  float Srow = 0.f;
  int4 kv = *(const int4*)(k2 + base + (size_t)sr * HD + scol);
#pragma unroll
  for (int kt = 0; kt < 8; kt++) {
    *(int4*)&Ks[sr][scol] = kv;
    __syncthreads();
    if (kt < 7)
      kv = *(const int4*)(k2 + base + (size_t)((kt + 1) * 64 + sr) * HD + scol);
    float psum = 0.f;
#pragma unroll
    for (int f = 0; f < 4; f++) {
      v4i kf = *(const v4i*)&Ks[16 * f + c16][quad * 16];
      v4i d2 = (v4i){0, 0, 0, 0};
      d2 = __builtin_amdgcn_mfma_i32_16x16x64_i8(kf, qf, d2, 0, 0, 0);
      uint32_t pk = 0;
#pragma unroll
      for (int r = 0; r < 4; r++) {
        float e = truncf(fmul(coef128, (float)d2[r]));
        int mi = (int)rintf(fmul(e, 0.0078125f));
        psum = fadd(psum, ldexpf(1.0f, mi));
        pk |= ((uint32_t)(uint8_t)(int8_t)mi) << (8 * r);
      }
      mpack[kt][f] = pk;
    }
    psum = fadd(psum, __shfl_xor(psum, 16, 64));
    psum = fadd(psum, __shfl_xor(psum, 32, 64));
    Srow = fadd(Srow, psum);
    __syncthreads();
  }
  const float u = fdiv(fdiv(1.0f, Srow), attnm);

  // ---- pass B: requantize from register m, AV ----
  v4i xacc[4];
#pragma unroll
  for (int s2 = 0; s2 < 4; s2++) xacc[s2] = (v4i){0, 0, 0, 0};

  int4 vv = *(const int4*)(v2t + ((size_t)bh * HD + sr) * NN + scol);
#pragma unroll
  for (int kt = 0; kt < 8; kt++) {
    *(int4*)&Vt[sr][scol] = vv;
    __syncthreads();
    if (kt < 7)
      vv = *(const int4*)(v2t + ((size_t)bh * HD + sr) * NN + (kt + 1) * 64 +
                          scol);
#pragma unroll
    for (int f = 0; f < 4; f++) {
      uint32_t pk = mpack[kt][f];
      uint32_t wpk = 0;
#pragma unroll
      for (int r = 0; r < 4; r++) {
        int mi = (int)(int8_t)(pk >> (8 * r));
        float t = fminf(ldexpf(u, mi), 7.f);
        wpk |= ((uint32_t)(uint8_t)(int8_t)rintf(t)) << (8 * r);
      }
      *(uint32_t*)&At[16 * w + c16][16 * f + 4 * quad] = wpk;
    }
    asm volatile("s_waitcnt lgkmcnt(0)" ::: "memory");
    v4i af = *(const v4i*)&At[16 * w + c16][quad * 16];
#pragma unroll
    for (int s2 = 0; s2 < 4; s2++) {
      v4i vf = *(const v4i*)&Vt[16 * s2 + c16][quad * 16];
      xacc[s2] = __builtin_amdgcn_mfma_i32_16x16x64_i8(vf, af, xacc[s2], 0, 0, 0);
    }
    __syncthreads();
  }

  const float pa = fdiv(scal[5], fmul(attnm, scal[3]));
#pragma unroll
  for (int s2 = 0; s2 < 4; s2++) {
    uint32_t pack = 0;
#pragma unroll
    for (int r = 0; r < 4; r++) {
      float t = fminf(fmaxf(fdiv((float)xacc[s2][r], pa), -4.f), 3.f);
      pack |= ((uint32_t)(uint8_t)(int8_t)rintf(t)) << (8 * r);
    }
    *(uint32_t*)&Ks[16 * w + c16][16 * s2 + 4 * quad] = pack;
  }
  __syncthreads();
  int4 ov = *(const int4*)&Ks[sr][scol];
  *(int4*)(x1q + ((size_t)bh * NN + qt * 64 + sr) * HD + scol) = ov;
}

// ---------------------------------------------------------------------------
// GEMM2 (i8 MFMA 32x32x32): barrier-free, LDS-free.  K-loop unroll 1 with
// K=32 half-steps.  XCD-affine: 12 column-blocks per x1q row-slice on one XCD.
// ---------------------------------------------------------------------------
__global__ __launch_bounds__(256, 4) void gemm_proj_kernel(
    const int8_t* __restrict__ x1q, const int8_t* __restrict__ Wq,
    const float* __restrict__ proj_alpha, const float* __restrict__ proj_bias,
    const float* __restrict__ scal, float* __restrict__ out) {
  const int L = blockIdx.x;
  const int xcd = L & 7, s = L >> 3;
  const int rb = xcd + 8 * (s / 12);   // row-slice 0..63 (XCD-resident)
  const int g = s % 12;                // column block 0..11
  const int tid = threadIdx.x;
  const int w = tid >> 6, lane = tid & 63;
  const int l31 = lane & 31, hi = lane >> 5;
  const int col0 = g * 64;
  const int b_idx = rb >> 1, nbase = (rb & 1) * 256;
  const int w64 = w * 64;

  v16i acc[2][2];
#pragma unroll
  for (int i = 0; i < 2; i++)
#pragma unroll
    for (int j = 0; j < 2; j++) acc[i][j] = (v16i)(0);

  const int8_t* pa0 =
      x1q + ((size_t)b_idx * HH * NN + nbase + w64 + l31) * 64 + hi * 16;
  const int8_t* pa1 = pa0 + 32 * 64;
  const int8_t* pb0 = Wq + ((size_t)(col0 + l31)) * 64 + hi * 16;
  const int8_t* pb1 = pb0 + 32 * 64;
  const size_t KTX = (size_t)NN * 64;  // head stride in x1q

#pragma unroll 1
  for (int kt = 0; kt < 12; kt++) {
    {
      v4i A0 = *(const v4i*)(pa0 + kt * KTX);
      v4i A1 = *(const v4i*)(pa1 + kt * KTX);
      v4i B0 = *(const v4i*)(pb0 + kt * KTP);
      v4i B1 = *(const v4i*)(pb1 + kt * KTP);
      acc[0][0] = __builtin_amdgcn_mfma_i32_32x32x32_i8(B0, A0, acc[0][0], 0, 0, 0);
      acc[0][1] = __builtin_amdgcn_mfma_i32_32x32x32_i8(B0, A1, acc[0][1], 0, 0, 0);
      acc[1][0] = __builtin_amdgcn_mfma_i32_32x32x32_i8(B1, A0, acc[1][0], 0, 0, 0);
      acc[1][1] = __builtin_amdgcn_mfma_i32_32x32x32_i8(B1, A1, acc[1][1], 0, 0, 0);
    }
    {
      v4i A0 = *(const v4i*)(pa0 + kt * KTX + 32);
      v4i A1 = *(const v4i*)(pa1 + kt * KTX + 32);
      v4i B0 = *(const v4i*)(pb0 + kt * KTP + 32);
      v4i B1 = *(const v4i*)(pb1 + kt * KTP + 32);
      acc[0][0] = __builtin_amdgcn_mfma_i32_32x32x32_i8(B0, A0, acc[0][0], 0, 0, 0);
      acc[0][1] = __builtin_amdgcn_mfma_i32_32x32x32_i8(B0, A1, acc[0][1], 0, 0, 0);
      acc[1][0] = __builtin_amdgcn_mfma_i32_32x32x32_i8(B1, A0, acc[1][0], 0, 0, 0);
      acc[1][1] = __builtin_amdgcn_mfma_i32_32x32x32_i8(B1, A1, acc[1][1], 0, 0, 0);
    }
  }

  const float pact = scal[5];
  const int seqbase = rb * 256 + w64;
#pragma unroll
  for (int i = 0; i < 2; i++)
#pragma unroll
    for (int b = 0; b < 4; b++) {
      int colb = col0 + 32 * i + 8 * b + 4 * hi;
      float4 al = *(const float4*)(proj_alpha + colb);
      float4 bi = *(const float4*)(proj_bias + colb);
      const float* alp = (const float*)&al;
      const float* bip = (const float*)&bi;
#pragma unroll
      for (int j = 0; j < 2; j++) {
        int m = seqbase + 32 * j + l31;
        float4 o;
        float* op = (float*)&o;
#pragma unroll
        for (int c = 0; c < 4; c++)
          op[c] = fadd(fmul(fmul((float)acc[i][j][4 * b + c], alp[c]), pact),
                       bip[c]);
        *(float4*)(out + (size_t)m * CC + colb) = o;
      }
    }
}

extern "C" void kernel_launch(void* const* d_in, const int* in_sizes, int n_in,
                              void* d_out, int out_size, void* d_ws,
                              size_t ws_size, hipStream_t stream) {
  const float* x0 = (const float*)d_in[0];
  const float* qkv_w = (const float*)d_in[1];
  const float* qkv_alpha = (const float*)d_in[2];
  const float* qkv_bias = (const float*)d_in[3];
  const float* qkv_act_alpha = (const float*)d_in[4];
  const float* proj_w = (const float*)d_in[5];
  const float* proj_alpha = (const float*)d_in[6];
  const float* proj_bias = (const float*)d_in[7];
  const float* proj_act_alpha = (const float*)d_in[8];
  const float* normq_w = (const float*)d_in[9];
  const float* normq_b = (const float*)d_in[10];
  const float* normk_w = (const float*)d_in[11];
  const float* normk_b = (const float*)d_in[12];
  const float* qact_alpha = (const float*)d_in[13];
  const float* kact_alpha = (const float*)d_in[14];
  const float* vact_alpha = (const float*)d_in[15];
  const float* attnact_alpha = (const float*)d_in[16];

  char* ws = (char*)d_ws;
  size_t off = 0;
  auto alloc = [&](size_t bytes) -> char* {
    char* p = ws + off;
    off += (bytes + 255) & ~(size_t)255;
    return p;
  };
  float* scal = (float*)alloc(64 * 4);
  float* qparams = (float*)alloc(256 * 4);
  float* biasq = (float*)alloc(QKV_C * 4);
  int8_t* x0q = (int8_t*)alloc((size_t)M_ROWS * CC);   // tiled [12][16384][64]
  int8_t* wq = (int8_t*)alloc((size_t)QKV_C * CC);     // tiled [12][2304][64]
  int8_t* pwq = (int8_t*)alloc((size_t)CC * CC);       // tiled [12][768][64]
  int8_t* q2 = (int8_t*)alloc((size_t)BB * HH * NN * HD);
  int8_t* k2 = (int8_t*)alloc((size_t)BB * HH * NN * HD);
  int8_t* v2t = (int8_t*)alloc((size_t)BB * HH * NN * HD);
  int8_t* x1q = (int8_t*)alloc((size_t)M_ROWS * CC);

  prep_kernel<<<1, 256, 0, stream>>>(qkv_act_alpha, proj_act_alpha, qact_alpha,
                                     kact_alpha, vact_alpha, attnact_alpha,
                                     normq_w, normq_b, normk_w, normk_b,
                                     qkv_bias, qkv_alpha, scal, qparams, biasq);

  int total4 = M_ROWS * CC / 4;
  quant_x0_kernel<<<(total4 + 255) / 256, 256, 0, stream>>>(x0, scal, x0q,
                                                            total4);
  quant_w_kernel<<<(QKV_C * CC + 255) / 256, 256, 0, stream>>>(
      qkv_w, qkv_alpha, wq, QKV_C, QKV_C * CC);
  quant_w_kernel<<<(CC * CC + 255) / 256, 256, 0, stream>>>(
      proj_w, proj_alpha, pwq, CC, CC * CC);

  gemm_qkv_kernel<<<QKV_C / 64 * (M_ROWS / 256), 256, 0, stream>>>(
      x0q, wq, biasq, scal, qkv_alpha, qparams, q2, k2, v2t);

  attn_kernel<<<(NN / 64) * (BB * HH), 256, 0, stream>>>(q2, k2, v2t, scal,
                                                         x1q);

  gemm_proj_kernel<<<(CC / 64) * (M_ROWS / 256), 256, 0, stream>>>(
      x1q, pwq, proj_alpha, proj_bias, scal, (float*)d_out);
}

// Round 10
// 339.722 us; speedup vs baseline: 1.3275x; 1.1436x over previous
//
#include <hip/hip_runtime.h>
#include <stdint.h>

// ---------------------------------------------------------------------------
// Q_Attention: quantized ViT attention block, bit-faithful to the JAX/numpy ref.
// B=32, N=512, C=768, H=12, hd=64.  All GEMMs on i8 MFMA (int32 acc, exact).
// R10: halve the accumulator.  R5-R9 all spilled (WRITE 190-396 MB vs 38 real)
// with a 64-reg v16i acc[2][2]; the unified-file budget at (256,4) is 128 and
// a 64-wide acc leaves no room.  Wave tile is now 32seq x 64ch: acc = 2 v16i
// = 32 AGPRs; fragments 24; LN scratch 32 fp32 — everything fits, no scratch.
// Block = 128x64 (4 waves), barrier-free K-loop (6 loads : 4 MFMAs per K64),
// XCD-affine swizzle kept.  Arithmetic order identical to verified rounds.
// ---------------------------------------------------------------------------

#define BB 32
#define NN 512
#define CC 768
#define HH 12
#define HD 64
#define M_ROWS (BB * NN)     // 16384
#define QKV_C (3 * CC)       // 2304
#define KTA ((size_t)M_ROWS * 64)   // x0q kt-slice stride
#define KTB ((size_t)QKV_C * 64)    // wq  kt-slice stride
#define KTP ((size_t)CC * 64)       // pwq kt-slice stride

typedef int v4i __attribute__((ext_vector_type(4)));
typedef int v16i __attribute__((ext_vector_type(16)));

__device__ __forceinline__ float fadd(float a, float b) { return __fadd_rn(a, b); }
__device__ __forceinline__ float fmul(float a, float b) { return __fmul_rn(a, b); }
__device__ __forceinline__ float fdiv(float a, float b) { return __fdiv_rn(a, b); }
__device__ __forceinline__ float fsub(float a, float b) { return __fsub_rn(a, b); }

// numpy pairwise_sum, n=96 (no remainder): 8 accumulators, then pairwise combine
__device__ float np_sum_96(const float* a) {
  float r[8];
#pragma unroll
  for (int j = 0; j < 8; j++) r[j] = a[j];
  for (int i = 8; i < 96; i += 8)
#pragma unroll
    for (int j = 0; j < 8; j++) r[j] = fadd(r[j], a[i + j]);
  return fadd(fadd(fadd(r[0], r[1]), fadd(r[2], r[3])),
              fadd(fadd(r[4], r[5]), fadd(r[6], r[7])));
}

// numpy pairwise mean of 12: 8-acc combine + 4 sequential remainder adds
__device__ float np_mean_12(const float* a) {
  float r[8];
#pragma unroll
  for (int j = 0; j < 8; j++) r[j] = a[j];
  float res = fadd(fadd(fadd(r[0], r[1]), fadd(r[2], r[3])),
                   fadd(fadd(r[4], r[5]), fadd(r[6], r[7])));
  res = fadd(res, a[8]);
  res = fadd(res, a[9]);
  res = fadd(res, a[10]);
  res = fadd(res, a[11]);
  return fdiv(res, 12.0f);
}

// ---------------------------------------------------------------------------
// prep: scalar means + folded LN quant params + integer qkv bias
// scal: [0]=a_in [1]=qact_m [2]=kact_m [3]=vact_m [4]=attnact_m [5]=pact_m
// qparams: [0:64]=qalpha [64:128]=qbias [128:192]=kalpha [192:256]=kbias
// ---------------------------------------------------------------------------
__global__ void prep_kernel(const float* __restrict__ qkv_act_alpha,
                            const float* __restrict__ proj_act_alpha,
                            const float* __restrict__ qact_alpha,
                            const float* __restrict__ kact_alpha,
                            const float* __restrict__ vact_alpha,
                            const float* __restrict__ attnact_alpha,
                            const float* __restrict__ normq_w,
                            const float* __restrict__ normq_b,
                            const float* __restrict__ normk_w,
                            const float* __restrict__ normk_b,
                            const float* __restrict__ qkv_bias,
                            const float* __restrict__ qkv_alpha,
                            float* __restrict__ scal,
                            float* __restrict__ qparams,
                            float* __restrict__ biasq) {
  __shared__ float s_scal[8];
  __shared__ float chunk[16];
  int tid = threadIdx.x;
  if (tid < 8) chunk[tid] = np_sum_96(qkv_act_alpha + 96 * tid);
  else if (tid < 16) chunk[tid] = np_sum_96(proj_act_alpha + 96 * (tid - 8));
  if (tid == 16) s_scal[1] = np_mean_12(qact_alpha);
  if (tid == 17) s_scal[2] = np_mean_12(kact_alpha);
  if (tid == 18) s_scal[3] = np_mean_12(vact_alpha);
  if (tid == 19) s_scal[4] = np_mean_12(attnact_alpha);
  __syncthreads();
  if (tid == 0) {
    float s0 = fadd(fadd(chunk[0], chunk[1]), fadd(chunk[2], chunk[3]));
    float s1 = fadd(fadd(chunk[4], chunk[5]), fadd(chunk[6], chunk[7]));
    s_scal[0] = fdiv(fadd(s0, s1), 768.0f);
    float p0 = fadd(fadd(chunk[8], chunk[9]), fadd(chunk[10], chunk[11]));
    float p1 = fadd(fadd(chunk[12], chunk[13]), fadd(chunk[14], chunk[15]));
    s_scal[5] = fdiv(fadd(p0, p1), 768.0f);
  }
  __syncthreads();
  if (tid < 6) scal[tid] = s_scal[tid];
  if (tid < 64) {
    qparams[tid]       = fdiv(s_scal[1], normq_w[tid]);    // act_a / nw
    qparams[64 + tid]  = fdiv(normq_b[tid], normq_w[tid]); // nb / nw
    qparams[128 + tid] = fdiv(s_scal[2], normk_w[tid]);
    qparams[192 + tid] = fdiv(normk_b[tid], normk_w[tid]);
  }
  float a_in = s_scal[0];
  for (int c = tid; c < QKV_C; c += blockDim.x)
    biasq[c] = truncf(fdiv(fdiv(qkv_bias[c], a_in), qkv_alpha[c]));
}

// x0_q = round(clip(x0 / a_in, -8, 7)) -> int8, K-TILED layout [12][16384][64]
__global__ void quant_x0_kernel(const float* __restrict__ x0,
                                const float* __restrict__ scal,
                                int8_t* __restrict__ x0q, int total4) {
  int i = blockIdx.x * blockDim.x + threadIdx.x;
  if (i >= total4) return;
  float a_in = scal[0];
  float4 v = ((const float4*)x0)[i];
  char4 o;
  o.x = (int8_t)rintf(fminf(fmaxf(fdiv(v.x, a_in), -8.f), 7.f));
  o.y = (int8_t)rintf(fminf(fmaxf(fdiv(v.y, a_in), -8.f), 7.f));
  o.z = (int8_t)rintf(fminf(fmaxf(fdiv(v.z, a_in), -8.f), 7.f));
  o.w = (int8_t)rintf(fminf(fmaxf(fdiv(v.w, a_in), -8.f), 7.f));
  int seq = i / 192;
  int kp = (i - seq * 192) * 4;
  *(char4*)(x0q + ((size_t)(kp >> 6) * M_ROWS + seq) * 64 + (kp & 63)) = o;
}

// row-wise 4-bit weight quant -> K-TILED layout [CC/64][rows][64]
__global__ void quant_w_kernel(const float* __restrict__ w,
                               const float* __restrict__ alpha,
                               int8_t* __restrict__ wq, int rows, int total) {
  int i = blockIdx.x * blockDim.x + threadIdx.x;
  if (i >= total) return;
  int row = i / CC;
  int k = i - row * CC;
  float t = fminf(fmaxf(fdiv(w[i], alpha[row]), -8.f), 7.f);
  wq[((size_t)(k >> 6) * rows + row) * 64 + (k & 63)] =
      (int8_t)rintf(t);
}

// ---------------------------------------------------------------------------
// GEMM1 (i8 MFMA 32x32x32): barrier-free.  Block = 128seq x 64ch; 4 waves
// each own 32seq x 64ch (acc = 2 v16i = 32 AGPRs).  XCD-affine: xcd = L&7;
// rb = xcd + 8*(s/36) (128-row A slice); g = s%36 -> 36 sharers per XCD.
// q/k: D = W*X^T (lane: seq=l31, ch=32i+8b+4hi+c); LN in registers, numpy
// 8-acc order, shfl_xor(32) lane-pair combine.  v: D = X*W^T (lane: ch=
// 32sj+l31, seq=8b+4hi+c) -> dword-packed transpose.  Wave-private packT.
// ---------------------------------------------------------------------------
__global__ __launch_bounds__(256, 4) void gemm_qkv_kernel(
    const int8_t* __restrict__ Aq, const int8_t* __restrict__ Wq,
    const float* __restrict__ biasq, const float* __restrict__ scal,
    const float* __restrict__ qkv_alpha, const float* __restrict__ qparams,
    int8_t* __restrict__ q2, int8_t* __restrict__ k2,
    int8_t* __restrict__ v2t) {
  __shared__ __align__(16) int8_t packT[4][3072];  // per-wave pack tile

  const int L = blockIdx.x;
  const int xcd = L & 7, s = L >> 3;
  const int rb = xcd + 8 * (s / 36);   // A 128-row slice 0..127 (XCD-resident)
  const int g = s % 36;                // column head 0..35
  const int tid = threadIdx.x;
  const int w = tid >> 6, lane = tid & 63;
  const int l31 = lane & 31, hi = lane >> 5;
  const int sec = g / HH, head = g % HH;
  const int col0 = g * 64;
  const int b_idx = rb >> 2, nbase = (rb & 3) * 128;
  const int w32 = w * 32;
  const size_t bh = (size_t)b_idx * HH + head;

  v16i acc0 = (v16i)(0), acc1 = (v16i)(0);

  const int8_t* pa = Aq + ((size_t)(rb * 128 + w32 + l31)) * 64 + hi * 16;
  const int8_t* pb0 = Wq + ((size_t)(col0 + l31)) * 64 + hi * 16;
  const int8_t* pb1 = pb0 + 32 * 64;

  if (sec < 2) {  // q/k: D = W * X^T
#pragma unroll 1
    for (int kt = 0; kt < 12; kt++) {
      v4i Aa = *(const v4i*)(pa + kt * KTA);
      v4i Ab = *(const v4i*)(pa + kt * KTA + 32);
      v4i B0a = *(const v4i*)(pb0 + kt * KTB);
      v4i B0b = *(const v4i*)(pb0 + kt * KTB + 32);
      v4i B1a = *(const v4i*)(pb1 + kt * KTB);
      v4i B1b = *(const v4i*)(pb1 + kt * KTB + 32);
      acc0 = __builtin_amdgcn_mfma_i32_32x32x32_i8(B0a, Aa, acc0, 0, 0, 0);
      acc1 = __builtin_amdgcn_mfma_i32_32x32x32_i8(B1a, Aa, acc1, 0, 0, 0);
      acc0 = __builtin_amdgcn_mfma_i32_32x32x32_i8(B0b, Ab, acc0, 0, 0, 0);
      acc1 = __builtin_amdgcn_mfma_i32_32x32x32_i8(B1b, Ab, acc1, 0, 0, 0);
    }
    // ---- LN epilogue (lane: seq=l31, ch=32i+8b+4hi+c; 32 fp32 scratch) ----
    float xs[2][16];
#pragma unroll
    for (int i = 0; i < 2; i++)
#pragma unroll
      for (int b = 0; b < 4; b++) {
        int cg = col0 + 32 * i + 8 * b + 4 * hi;
        float4 bqv = *(const float4*)(biasq + cg);
        float4 alv = *(const float4*)(qkv_alpha + cg);
        const float* bqp = (const float*)&bqv;
        const float* alp = (const float*)&alv;
#pragma unroll
        for (int c = 0; c < 4; c++) {
          int av = (i == 0) ? acc0[4 * b + c] : acc1[4 * b + c];
          xs[i][4 * b + c] = fmul(fadd((float)av, bqp[c]), alp[c]);
        }
      }
    // numpy-order stats: acc idx = ch&7 = 4hi+c (lane-local), t = ch>>3 = 4i+b
    float rc[4];
#pragma unroll
    for (int c = 0; c < 4; c++) rc[c] = xs[0][c];
#pragma unroll
    for (int b = 1; b < 4; b++)
#pragma unroll
      for (int c = 0; c < 4; c++) rc[c] = fadd(rc[c], xs[0][4 * b + c]);
#pragma unroll
    for (int b = 0; b < 4; b++)
#pragma unroll
      for (int c = 0; c < 4; c++) rc[c] = fadd(rc[c], xs[1][4 * b + c]);
    float Ls = fadd(fadd(rc[0], rc[1]), fadd(rc[2], rc[3]));
    float Rs = __shfl_xor(Ls, 32, 64);
    float mn = fdiv(fadd(Ls, Rs), 64.0f);  // fadd commutative: lanes agree
    float vc[4];
#pragma unroll
    for (int c = 0; c < 4; c++) {
      float d = fsub(xs[0][c], mn);
      vc[c] = fmul(d, d);
    }
#pragma unroll
    for (int b = 1; b < 4; b++)
#pragma unroll
      for (int c = 0; c < 4; c++) {
        float d = fsub(xs[0][4 * b + c], mn);
        vc[c] = fadd(vc[c], fmul(d, d));
      }
#pragma unroll
    for (int b = 0; b < 4; b++)
#pragma unroll
      for (int c = 0; c < 4; c++) {
        float d = fsub(xs[1][4 * b + c], mn);
        vc[c] = fadd(vc[c], fmul(d, d));
      }
    float Lv = fadd(fadd(vc[0], vc[1]), fadd(vc[2], vc[3]));
    float Rv = __shfl_xor(Lv, 32, 64);
    float var = fdiv(fadd(Lv, Rv), 63.0f);
    float den = fadd(__fsqrt_rn(var), 1e-5f);
    const float* ap = qparams + (sec == 0 ? 0 : 128);
#pragma unroll
    for (int i = 0; i < 2; i++)
#pragma unroll
      for (int b = 0; b < 4; b++) {
        int cin = 32 * i + 8 * b + 4 * hi;  // channel-in-head
        float4 a4 = *(const float4*)(ap + cin);
        float4 b4 = *(const float4*)(ap + 64 + cin);
        const float* a4p = (const float*)&a4;
        const float* b4p = (const float*)&b4;
        uint32_t pk = 0;
#pragma unroll
        for (int c = 0; c < 4; c++) {
          float xn = fdiv(fsub(xs[i][4 * b + c], mn), den);
          float t = fdiv(fadd(xn, b4p[c]), a4p[c]);
          t = fminf(fmaxf(t, -4.f), 3.f);
          pk |= ((uint32_t)(uint8_t)(int8_t)rintf(t)) << (8 * c);
        }
        *(uint32_t*)&packT[w][l31 * 80 + cin] = pk;
      }
    asm volatile("s_waitcnt lgkmcnt(0)" ::: "memory");
    int8_t* dst = (sec == 0) ? q2 : k2;
    size_t rowbase = bh * NN + nbase + w32;
#pragma unroll
    for (int c = 0; c < 2; c++) {
      int id = lane + 64 * c;
      int row = id >> 2, off = (id & 3) * 16;  // 32 rows x 64 B
      int4 ov = *(const int4*)&packT[w][row * 80 + off];
      *(int4*)(dst + (rowbase + row) * 64 + off) = ov;
    }
  } else {  // v: D = X * W^T (lane: ch = 32sj + l31, seq = 8b+4hi+c)
#pragma unroll 1
    for (int kt = 0; kt < 12; kt++) {
      v4i Aa = *(const v4i*)(pa + kt * KTA);
      v4i Ab = *(const v4i*)(pa + kt * KTA + 32);
      v4i B0a = *(const v4i*)(pb0 + kt * KTB);
      v4i B0b = *(const v4i*)(pb0 + kt * KTB + 32);
      v4i B1a = *(const v4i*)(pb1 + kt * KTB);
      v4i B1b = *(const v4i*)(pb1 + kt * KTB + 32);
      acc0 = __builtin_amdgcn_mfma_i32_32x32x32_i8(Aa, B0a, acc0, 0, 0, 0);
      acc1 = __builtin_amdgcn_mfma_i32_32x32x32_i8(Aa, B1a, acc1, 0, 0, 0);
      acc0 = __builtin_amdgcn_mfma_i32_32x32x32_i8(Ab, B0b, acc0, 0, 0, 0);
      acc1 = __builtin_amdgcn_mfma_i32_32x32x32_i8(Ab, B1b, acc1, 0, 0, 0);
    }
    const float a_in = scal[0], vact = scal[3];
#pragma unroll
    for (int sj = 0; sj < 2; sj++) {
      int cg = col0 + 32 * sj + l31;
      float bq = biasq[cg];
      float va = fdiv(vact, fmul(a_in, qkv_alpha[cg]));
      int dloc = 32 * sj + l31;
#pragma unroll
      for (int b = 0; b < 4; b++) {
        uint32_t pk = 0;
#pragma unroll
        for (int c = 0; c < 4; c++) {
          int av = (sj == 0) ? acc0[4 * b + c] : acc1[4 * b + c];
          float vint = fadd((float)av, bq);
          float t = fminf(fmaxf(fdiv(vint, va), -4.f), 3.f);
          pk |= ((uint32_t)(uint8_t)(int8_t)rintf(t)) << (8 * c);
        }
        *(uint32_t*)&packT[w][dloc * 48 + 8 * b + 4 * hi] = pk;
      }
    }
    asm volatile("s_waitcnt lgkmcnt(0)" ::: "memory");
#pragma unroll
    for (int c = 0; c < 2; c++) {
      int id = lane + 64 * c;
      int row = id >> 1, off = (id & 1) * 16;  // 64 d-rows x 32 B
      int4 ov = *(const int4*)&packT[w][row * 48 + off];
      *(int4*)(v2t + (bh * HD + row) * NN + nbase + w32 + off) = ov;
    }
  }
}

// ---------------------------------------------------------------------------
// Attention (i8 MFMA), per (qtile64, b*h).  XCD-affine decode: the 8 qt-blocks
// of one (b,h) head run consecutively on one XCD -> K/V head L2-resident.
// ---------------------------------------------------------------------------
__global__ __launch_bounds__(256) void attn_kernel(
    const int8_t* __restrict__ q2, const int8_t* __restrict__ k2,
    const int8_t* __restrict__ v2t, const float* __restrict__ scal,
    int8_t* __restrict__ x1q) {
  __shared__ __align__(16) int8_t Qs[64][80];
  __shared__ __align__(16) int8_t Ks[64][80];
  __shared__ __align__(16) int8_t Vt[64][80];
  __shared__ __align__(16) int8_t At[64][80];

  const int L = blockIdx.x;
  const int xcd = L & 7, s = L >> 3;
  const int bh = xcd + 8 * (s >> 3);   // head 0..383 (XCD-resident K/V)
  const int qt = s & 7;                // q tile 0..7
  const int tid = threadIdx.x;
  const int w = tid >> 6, lane = tid & 63, quad = lane >> 4, c16 = lane & 15;
  const int sr = tid >> 2, scol = (tid & 3) << 4;
  const float attnm = scal[4];
  const float coef =
      fmul(1.4426950408889634f, fmul(fmul(0.125f, scal[1]), scal[2]));
  const float coef128 = fmul(coef, 128.f);
  const size_t base = (size_t)bh * NN * HD;

  *(int4*)&Qs[sr][scol] =
      *(const int4*)(q2 + base + (size_t)(qt * 64 + sr) * HD + scol);
  __syncthreads();
  v4i qf = *(const v4i*)&Qs[16 * w + c16][quad * 16];

  // ---- pass A: QK^T, m -> registers, row sums of 2^m ----
  uint32_t mpack[8][4];
  float Srow = 0.f;
  int4 kv = *(const int4*)(k2 + base + (size_t)sr * HD + scol);
#pragma unroll
  for (int kt = 0; kt < 8; kt++) {
    *(int4*)&Ks[sr][scol] = kv;
    __syncthreads();
    if (kt < 7)
      kv = *(const int4*)(k2 + base + (size_t)((kt + 1) * 64 + sr) * HD + scol);
    float psum = 0.f;
#pragma unroll
    for (int f = 0; f < 4; f++) {
      v4i kf = *(const v4i*)&Ks[16 * f + c16][quad * 16];
      v4i d2 = (v4i){0, 0, 0, 0};
      d2 = __builtin_amdgcn_mfma_i32_16x16x64_i8(kf, qf, d2, 0, 0, 0);
      uint32_t pk = 0;
#pragma unroll
      for (int r = 0; r < 4; r++) {
        float e = truncf(fmul(coef128, (float)d2[r]));
        int mi = (int)rintf(fmul(e, 0.0078125f));
        psum = fadd(psum, ldexpf(1.0f, mi));
        pk |= ((uint32_t)(uint8_t)(int8_t)mi) << (8 * r);
      }
      mpack[kt][f] = pk;
    }
    psum = fadd(psum, __shfl_xor(psum, 16, 64));
    psum = fadd(psum, __shfl_xor(psum, 32, 64));
    Srow = fadd(Srow, psum);
    __syncthreads();
  }
  const float u = fdiv(fdiv(1.0f, Srow), attnm);

  // ---- pass B: requantize from register m, AV ----
  v4i xacc[4];
#pragma unroll
  for (int s2 = 0; s2 < 4; s2++) xacc[s2] = (v4i){0, 0, 0, 0};

  int4 vv = *(const int4*)(v2t + ((size_t)bh * HD + sr) * NN + scol);
#pragma unroll
  for (int kt = 0; kt < 8; kt++) {
    *(int4*)&Vt[sr][scol] = vv;
    __syncthreads();
    if (kt < 7)
      vv = *(const int4*)(v2t + ((size_t)bh * HD + sr) * NN + (kt + 1) * 64 +
                          scol);
#pragma unroll
    for (int f = 0; f < 4; f++) {
      uint32_t pk = mpack[kt][f];
      uint32_t wpk = 0;
#pragma unroll
      for (int r = 0; r < 4; r++) {
        int mi = (int)(int8_t)(pk >> (8 * r));
        float t = fminf(ldexpf(u, mi), 7.f);
        wpk |= ((uint32_t)(uint8_t)(int8_t)rintf(t)) << (8 * r);
      }
      *(uint32_t*)&At[16 * w + c16][16 * f + 4 * quad] = wpk;
    }
    asm volatile("s_waitcnt lgkmcnt(0)" ::: "memory");
    v4i af = *(const v4i*)&At[16 * w + c16][quad * 16];
#pragma unroll
    for (int s2 = 0; s2 < 4; s2++) {
      v4i vf = *(const v4i*)&Vt[16 * s2 + c16][quad * 16];
      xacc[s2] = __builtin_amdgcn_mfma_i32_16x16x64_i8(vf, af, xacc[s2], 0, 0, 0);
    }
    __syncthreads();
  }

  const float pa = fdiv(scal[5], fmul(attnm, scal[3]));
#pragma unroll
  for (int s2 = 0; s2 < 4; s2++) {
    uint32_t pack = 0;
#pragma unroll
    for (int r = 0; r < 4; r++) {
      float t = fminf(fmaxf(fdiv((float)xacc[s2][r], pa), -4.f), 3.f);
      pack |= ((uint32_t)(uint8_t)(int8_t)rintf(t)) << (8 * r);
    }
    *(uint32_t*)&Ks[16 * w + c16][16 * s2 + 4 * quad] = pack;
  }
  __syncthreads();
  int4 ov = *(const int4*)&Ks[sr][scol];
  *(int4*)(x1q + ((size_t)bh * NN + qt * 64 + sr) * HD + scol) = ov;
}

// ---------------------------------------------------------------------------
// GEMM2 (i8 MFMA 32x32x32): barrier-free, LDS-free.  Block = 128seq x 64ch,
// wave = 32x64 (acc = 32 AGPRs).  XCD-affine: 12 column-blocks per x1q
// 128-row slice on one XCD.  D = W*X^T; float4 epilogue stores.
// ---------------------------------------------------------------------------
__global__ __launch_bounds__(256, 4) void gemm_proj_kernel(
    const int8_t* __restrict__ x1q, const int8_t* __restrict__ Wq,
    const float* __restrict__ proj_alpha, const float* __restrict__ proj_bias,
    const float* __restrict__ scal, float* __restrict__ out) {
  const int L = blockIdx.x;
  const int xcd = L & 7, s = L >> 3;
  const int rb = xcd + 8 * (s / 12);   // 128-row slice 0..127 (XCD-resident)
  const int g = s % 12;                // column block 0..11
  const int tid = threadIdx.x;
  const int w = tid >> 6, lane = tid & 63;
  const int l31 = lane & 31, hi = lane >> 5;
  const int col0 = g * 64;
  const int b_idx = rb >> 2, nbase = (rb & 3) * 128;
  const int w32 = w * 32;

  v16i acc0 = (v16i)(0), acc1 = (v16i)(0);

  const int8_t* pa =
      x1q + ((size_t)b_idx * HH * NN + nbase + w32 + l31) * 64 + hi * 16;
  const int8_t* pb0 = Wq + ((size_t)(col0 + l31)) * 64 + hi * 16;
  const int8_t* pb1 = pb0 + 32 * 64;
  const size_t KTX = (size_t)NN * 64;  // head stride in x1q

#pragma unroll 1
  for (int kt = 0; kt < 12; kt++) {
    v4i Aa = *(const v4i*)(pa + kt * KTX);
    v4i Ab = *(const v4i*)(pa + kt * KTX + 32);
    v4i B0a = *(const v4i*)(pb0 + kt * KTP);
    v4i B0b = *(const v4i*)(pb0 + kt * KTP + 32);
    v4i B1a = *(const v4i*)(pb1 + kt * KTP);
    v4i B1b = *(const v4i*)(pb1 + kt * KTP + 32);
    acc0 = __builtin_amdgcn_mfma_i32_32x32x32_i8(B0a, Aa, acc0, 0, 0, 0);
    acc1 = __builtin_amdgcn_mfma_i32_32x32x32_i8(B1a, Aa, acc1, 0, 0, 0);
    acc0 = __builtin_amdgcn_mfma_i32_32x32x32_i8(B0b, Ab, acc0, 0, 0, 0);
    acc1 = __builtin_amdgcn_mfma_i32_32x32x32_i8(B1b, Ab, acc1, 0, 0, 0);
  }

  const float pact = scal[5];
  const int m = rb * 128 + w32 + l31;
#pragma unroll
  for (int i = 0; i < 2; i++)
#pragma unroll
    for (int b = 0; b < 4; b++) {
      int colb = col0 + 32 * i + 8 * b + 4 * hi;
      float4 al = *(const float4*)(proj_alpha + colb);
      float4 bi = *(const float4*)(proj_bias + colb);
      const float* alp = (const float*)&al;
      const float* bip = (const float*)&bi;
      float4 o;
      float* op = (float*)&o;
#pragma unroll
      for (int c = 0; c < 4; c++) {
        int av = (i == 0) ? acc0[4 * b + c] : acc1[4 * b + c];
        op[c] = fadd(fmul(fmul((float)av, alp[c]), pact), bip[c]);
      }
      *(float4*)(out + (size_t)m * CC + colb) = o;
    }
}

extern "C" void kernel_launch(void* const* d_in, const int* in_sizes, int n_in,
                              void* d_out, int out_size, void* d_ws,
                              size_t ws_size, hipStream_t stream) {
  const float* x0 = (const float*)d_in[0];
  const float* qkv_w = (const float*)d_in[1];
  const float* qkv_alpha = (const float*)d_in[2];
  const float* qkv_bias = (const float*)d_in[3];
  const float* qkv_act_alpha = (const float*)d_in[4];
  const float* proj_w = (const float*)d_in[5];
  const float* proj_alpha = (const float*)d_in[6];
  const float* proj_bias = (const float*)d_in[7];
  const float* proj_act_alpha = (const float*)d_in[8];
  const float* normq_w = (const float*)d_in[9];
  const float* normq_b = (const float*)d_in[10];
  const float* normk_w = (const float*)d_in[11];
  const float* normk_b = (const float*)d_in[12];
  const float* qact_alpha = (const float*)d_in[13];
  const float* kact_alpha = (const float*)d_in[14];
  const float* vact_alpha = (const float*)d_in[15];
  const float* attnact_alpha = (const float*)d_in[16];

  char* ws = (char*)d_ws;
  size_t off = 0;
  auto alloc = [&](size_t bytes) -> char* {
    char* p = ws + off;
    off += (bytes + 255) & ~(size_t)255;
    return p;
  };
  float* scal = (float*)alloc(64 * 4);
  float* qparams = (float*)alloc(256 * 4);
  float* biasq = (float*)alloc(QKV_C * 4);
  int8_t* x0q = (int8_t*)alloc((size_t)M_ROWS * CC);   // tiled [12][16384][64]
  int8_t* wq = (int8_t*)alloc((size_t)QKV_C * CC);     // tiled [12][2304][64]
  int8_t* pwq = (int8_t*)alloc((size_t)CC * CC);       // tiled [12][768][64]
  int8_t* q2 = (int8_t*)alloc((size_t)BB * HH * NN * HD);
  int8_t* k2 = (int8_t*)alloc((size_t)BB * HH * NN * HD);
  int8_t* v2t = (int8_t*)alloc((size_t)BB * HH * NN * HD);
  int8_t* x1q = (int8_t*)alloc((size_t)M_ROWS * CC);

  prep_kernel<<<1, 256, 0, stream>>>(qkv_act_alpha, proj_act_alpha, qact_alpha,
                                     kact_alpha, vact_alpha, attnact_alpha,
                                     normq_w, normq_b, normk_w, normk_b,
                                     qkv_bias, qkv_alpha, scal, qparams, biasq);

  int total4 = M_ROWS * CC / 4;
  quant_x0_kernel<<<(total4 + 255) / 256, 256, 0, stream>>>(x0, scal, x0q,
                                                            total4);
  quant_w_kernel<<<(QKV_C * CC + 255) / 256, 256, 0, stream>>>(
      qkv_w, qkv_alpha, wq, QKV_C, QKV_C * CC);
  quant_w_kernel<<<(CC * CC + 255) / 256, 256, 0, stream>>>(
      proj_w, proj_alpha, pwq, CC, CC * CC);

  gemm_qkv_kernel<<<36 * (M_ROWS / 128), 256, 0, stream>>>(
      x0q, wq, biasq, scal, qkv_alpha, qparams, q2, k2, v2t);

  attn_kernel<<<(NN / 64) * (BB * HH), 256, 0, stream>>>(q2, k2, v2t, scal,
                                                         x1q);

  gemm_proj_kernel<<<12 * (M_ROWS / 128), 256, 0, stream>>>(
      x1q, pwq, proj_alpha, proj_bias, scal, (float*)d_out);
}

// Round 11
// 318.528 us; speedup vs baseline: 1.4159x; 1.0665x over previous
//
#include <hip/hip_runtime.h>
#include <stdint.h>

// ---------------------------------------------------------------------------
// Q_Attention: quantized ViT attention block, bit-faithful to the JAX/numpy ref.
// B=32, N=512, C=768, H=12, hd=64.  All GEMMs on i8 MFMA (int32 acc, exact).
// R11: R10 (spill-free 32x64 wave tiles, barrier-free, XCD-affine) +
// (a) launch_bounds(256,6): R10's 4-wave cap was the occupancy limiter
//     (44+32 regs would support 6 waves/SIMD);
// (b) fragment-major operand layout for x0q/wq/pwq: per 32-row group,
//     addr = (b>>4)*512 + (row&31)*16 + (b&15) -> every MFMA fragment load
//     is one fully-coalesced 1024B request (was 32 half-used lines).
// Same bytes to same lanes -> arithmetic identical (absmax 0 preserved).
// ---------------------------------------------------------------------------

#define BB 32
#define NN 512
#define CC 768
#define HH 12
#define HD 64
#define M_ROWS (BB * NN)     // 16384
#define QKV_C (3 * CC)       // 2304
#define KTA ((size_t)M_ROWS * 64)   // x0q kt-slice stride
#define KTB ((size_t)QKV_C * 64)    // wq  kt-slice stride
#define KTP ((size_t)CC * 64)       // pwq kt-slice stride

typedef int v4i __attribute__((ext_vector_type(4)));
typedef int v16i __attribute__((ext_vector_type(16)));

__device__ __forceinline__ float fadd(float a, float b) { return __fadd_rn(a, b); }
__device__ __forceinline__ float fmul(float a, float b) { return __fmul_rn(a, b); }
__device__ __forceinline__ float fdiv(float a, float b) { return __fdiv_rn(a, b); }
__device__ __forceinline__ float fsub(float a, float b) { return __fsub_rn(a, b); }

// numpy pairwise_sum, n=96 (no remainder): 8 accumulators, then pairwise combine
__device__ float np_sum_96(const float* a) {
  float r[8];
#pragma unroll
  for (int j = 0; j < 8; j++) r[j] = a[j];
  for (int i = 8; i < 96; i += 8)
#pragma unroll
    for (int j = 0; j < 8; j++) r[j] = fadd(r[j], a[i + j]);
  return fadd(fadd(fadd(r[0], r[1]), fadd(r[2], r[3])),
              fadd(fadd(r[4], r[5]), fadd(r[6], r[7])));
}

// numpy pairwise mean of 12: 8-acc combine + 4 sequential remainder adds
__device__ float np_mean_12(const float* a) {
  float r[8];
#pragma unroll
  for (int j = 0; j < 8; j++) r[j] = a[j];
  float res = fadd(fadd(fadd(r[0], r[1]), fadd(r[2], r[3])),
                   fadd(fadd(r[4], r[5]), fadd(r[6], r[7])));
  res = fadd(res, a[8]);
  res = fadd(res, a[9]);
  res = fadd(res, a[10]);
  res = fadd(res, a[11]);
  return fdiv(res, 12.0f);
}

// ---------------------------------------------------------------------------
// prep: scalar means + folded LN quant params + integer qkv bias
// scal: [0]=a_in [1]=qact_m [2]=kact_m [3]=vact_m [4]=attnact_m [5]=pact_m
// qparams: [0:64]=qalpha [64:128]=qbias [128:192]=kalpha [192:256]=kbias
// ---------------------------------------------------------------------------
__global__ void prep_kernel(const float* __restrict__ qkv_act_alpha,
                            const float* __restrict__ proj_act_alpha,
                            const float* __restrict__ qact_alpha,
                            const float* __restrict__ kact_alpha,
                            const float* __restrict__ vact_alpha,
                            const float* __restrict__ attnact_alpha,
                            const float* __restrict__ normq_w,
                            const float* __restrict__ normq_b,
                            const float* __restrict__ normk_w,
                            const float* __restrict__ normk_b,
                            const float* __restrict__ qkv_bias,
                            const float* __restrict__ qkv_alpha,
                            float* __restrict__ scal,
                            float* __restrict__ qparams,
                            float* __restrict__ biasq) {
  __shared__ float s_scal[8];
  __shared__ float chunk[16];
  int tid = threadIdx.x;
  if (tid < 8) chunk[tid] = np_sum_96(qkv_act_alpha + 96 * tid);
  else if (tid < 16) chunk[tid] = np_sum_96(proj_act_alpha + 96 * (tid - 8));
  if (tid == 16) s_scal[1] = np_mean_12(qact_alpha);
  if (tid == 17) s_scal[2] = np_mean_12(kact_alpha);
  if (tid == 18) s_scal[3] = np_mean_12(vact_alpha);
  if (tid == 19) s_scal[4] = np_mean_12(attnact_alpha);
  __syncthreads();
  if (tid == 0) {
    float s0 = fadd(fadd(chunk[0], chunk[1]), fadd(chunk[2], chunk[3]));
    float s1 = fadd(fadd(chunk[4], chunk[5]), fadd(chunk[6], chunk[7]));
    s_scal[0] = fdiv(fadd(s0, s1), 768.0f);
    float p0 = fadd(fadd(chunk[8], chunk[9]), fadd(chunk[10], chunk[11]));
    float p1 = fadd(fadd(chunk[12], chunk[13]), fadd(chunk[14], chunk[15]));
    s_scal[5] = fdiv(fadd(p0, p1), 768.0f);
  }
  __syncthreads();
  if (tid < 6) scal[tid] = s_scal[tid];
  if (tid < 64) {
    qparams[tid]       = fdiv(s_scal[1], normq_w[tid]);    // act_a / nw
    qparams[64 + tid]  = fdiv(normq_b[tid], normq_w[tid]); // nb / nw
    qparams[128 + tid] = fdiv(s_scal[2], normk_w[tid]);
    qparams[192 + tid] = fdiv(normk_b[tid], normk_w[tid]);
  }
  float a_in = s_scal[0];
  for (int c = tid; c < QKV_C; c += blockDim.x)
    biasq[c] = truncf(fdiv(fdiv(qkv_bias[c], a_in), qkv_alpha[c]));
}

// fragment-major address within a kt-slice: 32-row groups of 2KB;
// byte (row, b) -> (row&~31)*64 + (b>>4)*512 + (row&31)*16 + (b&15)
__device__ __forceinline__ size_t fragaddr(int row, int b) {
  return (size_t)(row & ~31) * 64 + ((b >> 4) * 512 + (row & 31) * 16 + (b & 15));
}

// x0_q = round(clip(x0 / a_in, -8, 7)) -> int8, fragment-major [12][...]
__global__ void quant_x0_kernel(const float* __restrict__ x0,
                                const float* __restrict__ scal,
                                int8_t* __restrict__ x0q, int total4) {
  int i = blockIdx.x * blockDim.x + threadIdx.x;
  if (i >= total4) return;
  float a_in = scal[0];
  float4 v = ((const float4*)x0)[i];
  char4 o;
  o.x = (int8_t)rintf(fminf(fmaxf(fdiv(v.x, a_in), -8.f), 7.f));
  o.y = (int8_t)rintf(fminf(fmaxf(fdiv(v.y, a_in), -8.f), 7.f));
  o.z = (int8_t)rintf(fminf(fmaxf(fdiv(v.z, a_in), -8.f), 7.f));
  o.w = (int8_t)rintf(fminf(fmaxf(fdiv(v.w, a_in), -8.f), 7.f));
  int seq = i / 192;
  int kp = (i - seq * 192) * 4;  // global channel, multiple of 4
  int b = kp & 63;
  *(char4*)(x0q + (size_t)(kp >> 6) * KTA + fragaddr(seq, b)) = o;
}

// row-wise 4-bit weight quant -> fragment-major [K/64][...]
__global__ void quant_w_kernel(const float* __restrict__ w,
                               const float* __restrict__ alpha,
                               int8_t* __restrict__ wq, int rows, int total) {
  int i = blockIdx.x * blockDim.x + threadIdx.x;
  if (i >= total) return;
  int row = i / CC;
  int k = i - row * CC;
  float t = fminf(fmaxf(fdiv(w[i], alpha[row]), -8.f), 7.f);
  wq[(size_t)(k >> 6) * ((size_t)rows * 64) + fragaddr(row, k)] =
      (int8_t)rintf(t);
}

// ---------------------------------------------------------------------------
// GEMM1 (i8 MFMA 32x32x32): barrier-free.  Block = 128seq x 64ch; 4 waves
// each own 32seq x 64ch (acc = 2 v16i = 32 AGPRs).  XCD-affine: xcd = L&7;
// rb = xcd + 8*(s/36) (128-row A slice); g = s%36 -> 36 sharers per XCD.
// Fragment-major layout: every operand load = one coalesced 1024B request.
// q/k: D = W*X^T; LN in registers (numpy 8-acc order, shfl_xor(32) combine).
// v: D = X*W^T -> dword-packed transpose.  launch_bounds(256,6).
// ---------------------------------------------------------------------------
__global__ __launch_bounds__(256, 6) void gemm_qkv_kernel(
    const int8_t* __restrict__ Aq, const int8_t* __restrict__ Wq,
    const float* __restrict__ biasq, const float* __restrict__ scal,
    const float* __restrict__ qkv_alpha, const float* __restrict__ qparams,
    int8_t* __restrict__ q2, int8_t* __restrict__ k2,
    int8_t* __restrict__ v2t) {
  __shared__ __align__(16) int8_t packT[4][3072];  // per-wave pack tile

  const int L = blockIdx.x;
  const int xcd = L & 7, s = L >> 3;
  const int rb = xcd + 8 * (s / 36);   // A 128-row slice 0..127 (XCD-resident)
  const int g = s % 36;                // column head 0..35
  const int tid = threadIdx.x;
  const int w = tid >> 6, lane = tid & 63;
  const int l31 = lane & 31, hi = lane >> 5;
  const int sec = g / HH, head = g % HH;
  const int col0 = g * 64;
  const int b_idx = rb >> 2, nbase = (rb & 3) * 128;
  const int w32 = w * 32;
  const size_t bh = (size_t)b_idx * HH + head;

  v16i acc0 = (v16i)(0), acc1 = (v16i)(0);

  // fragment-major pointers: lane offset = hi*512 + l31*16
  const int8_t* pa = Aq + (size_t)(rb * 128 + w32) * 64 + hi * 512 + l31 * 16;
  const int8_t* pb = Wq + (size_t)col0 * 64 + hi * 512 + l31 * 16;

  if (sec < 2) {  // q/k: D = W * X^T
#pragma unroll 1
    for (int kt = 0; kt < 12; kt++) {
      v4i Aa = *(const v4i*)(pa + kt * KTA);
      v4i Ab = *(const v4i*)(pa + kt * KTA + 1024);
      v4i B0a = *(const v4i*)(pb + kt * KTB);
      v4i B0b = *(const v4i*)(pb + kt * KTB + 1024);
      v4i B1a = *(const v4i*)(pb + kt * KTB + 2048);
      v4i B1b = *(const v4i*)(pb + kt * KTB + 3072);
      acc0 = __builtin_amdgcn_mfma_i32_32x32x32_i8(B0a, Aa, acc0, 0, 0, 0);
      acc1 = __builtin_amdgcn_mfma_i32_32x32x32_i8(B1a, Aa, acc1, 0, 0, 0);
      acc0 = __builtin_amdgcn_mfma_i32_32x32x32_i8(B0b, Ab, acc0, 0, 0, 0);
      acc1 = __builtin_amdgcn_mfma_i32_32x32x32_i8(B1b, Ab, acc1, 0, 0, 0);
    }
    // ---- LN epilogue (lane: seq=l31, ch=32i+8b+4hi+c; 32 fp32 scratch) ----
    float xs[2][16];
#pragma unroll
    for (int i = 0; i < 2; i++)
#pragma unroll
      for (int b = 0; b < 4; b++) {
        int cg = col0 + 32 * i + 8 * b + 4 * hi;
        float4 bqv = *(const float4*)(biasq + cg);
        float4 alv = *(const float4*)(qkv_alpha + cg);
        const float* bqp = (const float*)&bqv;
        const float* alp = (const float*)&alv;
#pragma unroll
        for (int c = 0; c < 4; c++) {
          int av = (i == 0) ? acc0[4 * b + c] : acc1[4 * b + c];
          xs[i][4 * b + c] = fmul(fadd((float)av, bqp[c]), alp[c]);
        }
      }
    // numpy-order stats: acc idx = ch&7 = 4hi+c (lane-local), t = ch>>3 = 4i+b
    float rc[4];
#pragma unroll
    for (int c = 0; c < 4; c++) rc[c] = xs[0][c];
#pragma unroll
    for (int b = 1; b < 4; b++)
#pragma unroll
      for (int c = 0; c < 4; c++) rc[c] = fadd(rc[c], xs[0][4 * b + c]);
#pragma unroll
    for (int b = 0; b < 4; b++)
#pragma unroll
      for (int c = 0; c < 4; c++) rc[c] = fadd(rc[c], xs[1][4 * b + c]);
    float Ls = fadd(fadd(rc[0], rc[1]), fadd(rc[2], rc[3]));
    float Rs = __shfl_xor(Ls, 32, 64);
    float mn = fdiv(fadd(Ls, Rs), 64.0f);  // fadd commutative: lanes agree
    float vc[4];
#pragma unroll
    for (int c = 0; c < 4; c++) {
      float d = fsub(xs[0][c], mn);
      vc[c] = fmul(d, d);
    }
#pragma unroll
    for (int b = 1; b < 4; b++)
#pragma unroll
      for (int c = 0; c < 4; c++) {
        float d = fsub(xs[0][4 * b + c], mn);
        vc[c] = fadd(vc[c], fmul(d, d));
      }
#pragma unroll
    for (int b = 0; b < 4; b++)
#pragma unroll
      for (int c = 0; c < 4; c++) {
        float d = fsub(xs[1][4 * b + c], mn);
        vc[c] = fadd(vc[c], fmul(d, d));
      }
    float Lv = fadd(fadd(vc[0], vc[1]), fadd(vc[2], vc[3]));
    float Rv = __shfl_xor(Lv, 32, 64);
    float var = fdiv(fadd(Lv, Rv), 63.0f);
    float den = fadd(__fsqrt_rn(var), 1e-5f);
    const float* ap = qparams + (sec == 0 ? 0 : 128);
#pragma unroll
    for (int i = 0; i < 2; i++)
#pragma unroll
      for (int b = 0; b < 4; b++) {
        int cin = 32 * i + 8 * b + 4 * hi;  // channel-in-head
        float4 a4 = *(const float4*)(ap + cin);
        float4 b4 = *(const float4*)(ap + 64 + cin);
        const float* a4p = (const float*)&a4;
        const float* b4p = (const float*)&b4;
        uint32_t pk = 0;
#pragma unroll
        for (int c = 0; c < 4; c++) {
          float xn = fdiv(fsub(xs[i][4 * b + c], mn), den);
          float t = fdiv(fadd(xn, b4p[c]), a4p[c]);
          t = fminf(fmaxf(t, -4.f), 3.f);
          pk |= ((uint32_t)(uint8_t)(int8_t)rintf(t)) << (8 * c);
        }
        *(uint32_t*)&packT[w][l31 * 80 + cin] = pk;
      }
    asm volatile("s_waitcnt lgkmcnt(0)" ::: "memory");
    int8_t* dst = (sec == 0) ? q2 : k2;
    size_t rowbase = bh * NN + nbase + w32;
#pragma unroll
    for (int c = 0; c < 2; c++) {
      int id = lane + 64 * c;
      int row = id >> 2, off = (id & 3) * 16;  // 32 rows x 64 B
      int4 ov = *(const int4*)&packT[w][row * 80 + off];
      *(int4*)(dst + (rowbase + row) * 64 + off) = ov;
    }
  } else {  // v: D = X * W^T (lane: ch = 32sj + l31, seq = 8b+4hi+c)
#pragma unroll 1
    for (int kt = 0; kt < 12; kt++) {
      v4i Aa = *(const v4i*)(pa + kt * KTA);
      v4i Ab = *(const v4i*)(pa + kt * KTA + 1024);
      v4i B0a = *(const v4i*)(pb + kt * KTB);
      v4i B0b = *(const v4i*)(pb + kt * KTB + 1024);
      v4i B1a = *(const v4i*)(pb + kt * KTB + 2048);
      v4i B1b = *(const v4i*)(pb + kt * KTB + 3072);
      acc0 = __builtin_amdgcn_mfma_i32_32x32x32_i8(Aa, B0a, acc0, 0, 0, 0);
      acc1 = __builtin_amdgcn_mfma_i32_32x32x32_i8(Aa, B1a, acc1, 0, 0, 0);
      acc0 = __builtin_amdgcn_mfma_i32_32x32x32_i8(Ab, B0b, acc0, 0, 0, 0);
      acc1 = __builtin_amdgcn_mfma_i32_32x32x32_i8(Ab, B1b, acc1, 0, 0, 0);
    }
    const float a_in = scal[0], vact = scal[3];
#pragma unroll
    for (int sj = 0; sj < 2; sj++) {
      int cg = col0 + 32 * sj + l31;
      float bq = biasq[cg];
      float va = fdiv(vact, fmul(a_in, qkv_alpha[cg]));
      int dloc = 32 * sj + l31;
#pragma unroll
      for (int b = 0; b < 4; b++) {
        uint32_t pk = 0;
#pragma unroll
        for (int c = 0; c < 4; c++) {
          int av = (sj == 0) ? acc0[4 * b + c] : acc1[4 * b + c];
          float vint = fadd((float)av, bq);
          float t = fminf(fmaxf(fdiv(vint, va), -4.f), 3.f);
          pk |= ((uint32_t)(uint8_t)(int8_t)rintf(t)) << (8 * c);
        }
        *(uint32_t*)&packT[w][dloc * 48 + 8 * b + 4 * hi] = pk;
      }
    }
    asm volatile("s_waitcnt lgkmcnt(0)" ::: "memory");
#pragma unroll
    for (int c = 0; c < 2; c++) {
      int id = lane + 64 * c;
      int row = id >> 1, off = (id & 1) * 16;  // 64 d-rows x 32 B
      int4 ov = *(const int4*)&packT[w][row * 48 + off];
      *(int4*)(v2t + (bh * HD + row) * NN + nbase + w32 + off) = ov;
    }
  }
}

// ---------------------------------------------------------------------------
// Attention (i8 MFMA), per (qtile64, b*h).  XCD-affine decode: the 8 qt-blocks
// of one (b,h) head run consecutively on one XCD -> K/V head L2-resident.
// ---------------------------------------------------------------------------
__global__ __launch_bounds__(256) void attn_kernel(
    const int8_t* __restrict__ q2, const int8_t* __restrict__ k2,
    const int8_t* __restrict__ v2t, const float* __restrict__ scal,
    int8_t* __restrict__ x1q) {
  __shared__ __align__(16) int8_t Qs[64][80];
  __shared__ __align__(16) int8_t Ks[64][80];
  __shared__ __align__(16) int8_t Vt[64][80];
  __shared__ __align__(16) int8_t At[64][80];

  const int L = blockIdx.x;
  const int xcd = L & 7, s = L >> 3;
  const int bh = xcd + 8 * (s >> 3);   // head 0..383 (XCD-resident K/V)
  const int qt = s & 7;                // q tile 0..7
  const int tid = threadIdx.x;
  const int w = tid >> 6, lane = tid & 63, quad = lane >> 4, c16 = lane & 15;
  const int sr = tid >> 2, scol = (tid & 3) << 4;
  const float attnm = scal[4];
  const float coef =
      fmul(1.4426950408889634f, fmul(fmul(0.125f, scal[1]), scal[2]));
  const float coef128 = fmul(coef, 128.f);
  const size_t base = (size_t)bh * NN * HD;

  *(int4*)&Qs[sr][scol] =
      *(const int4*)(q2 + base + (size_t)(qt * 64 + sr) * HD + scol);
  __syncthreads();
  v4i qf = *(const v4i*)&Qs[16 * w + c16][quad * 16];

  // ---- pass A: QK^T, m -> registers, row sums of 2^m ----
  uint32_t mpack[8][4];
  float Srow = 0.f;
  int4 kv = *(const int4*)(k2 + base + (size_t)sr * HD + scol);
#pragma unroll
  for (int kt = 0; kt < 8; kt++) {
    *(int4*)&Ks[sr][scol] = kv;
    __syncthreads();
    if (kt < 7)
      kv = *(const int4*)(k2 + base + (size_t)((kt + 1) * 64 + sr) * HD + scol);
    float psum = 0.f;
#pragma unroll
    for (int f = 0; f < 4; f++) {
      v4i kf = *(const v4i*)&Ks[16 * f + c16][quad * 16];
      v4i d2 = (v4i){0, 0, 0, 0};
      d2 = __builtin_amdgcn_mfma_i32_16x16x64_i8(kf, qf, d2, 0, 0, 0);
      uint32_t pk = 0;
#pragma unroll
      for (int r = 0; r < 4; r++) {
        float e = truncf(fmul(coef128, (float)d2[r]));
        int mi = (int)rintf(fmul(e, 0.0078125f));
        psum = fadd(psum, ldexpf(1.0f, mi));
        pk |= ((uint32_t)(uint8_t)(int8_t)mi) << (8 * r);
      }
      mpack[kt][f] = pk;
    }
    psum = fadd(psum, __shfl_xor(psum, 16, 64));
    psum = fadd(psum, __shfl_xor(psum, 32, 64));
    Srow = fadd(Srow, psum);
    __syncthreads();
  }
  const float u = fdiv(fdiv(1.0f, Srow), attnm);

  // ---- pass B: requantize from register m, AV ----
  v4i xacc[4];
#pragma unroll
  for (int s2 = 0; s2 < 4; s2++) xacc[s2] = (v4i){0, 0, 0, 0};

  int4 vv = *(const int4*)(v2t + ((size_t)bh * HD + sr) * NN + scol);
#pragma unroll
  for (int kt = 0; kt < 8; kt++) {
    *(int4*)&Vt[sr][scol] = vv;
    __syncthreads();
    if (kt < 7)
      vv = *(const int4*)(v2t + ((size_t)bh * HD + sr) * NN + (kt + 1) * 64 +
                          scol);
#pragma unroll
    for (int f = 0; f < 4; f++) {
      uint32_t pk = mpack[kt][f];
      uint32_t wpk = 0;
#pragma unroll
      for (int r = 0; r < 4; r++) {
        int mi = (int)(int8_t)(pk >> (8 * r));
        float t = fminf(ldexpf(u, mi), 7.f);
        wpk |= ((uint32_t)(uint8_t)(int8_t)rintf(t)) << (8 * r);
      }
      *(uint32_t*)&At[16 * w + c16][16 * f + 4 * quad] = wpk;
    }
    asm volatile("s_waitcnt lgkmcnt(0)" ::: "memory");
    v4i af = *(const v4i*)&At[16 * w + c16][quad * 16];
#pragma unroll
    for (int s2 = 0; s2 < 4; s2++) {
      v4i vf = *(const v4i*)&Vt[16 * s2 + c16][quad * 16];
      xacc[s2] = __builtin_amdgcn_mfma_i32_16x16x64_i8(vf, af, xacc[s2], 0, 0, 0);
    }
    __syncthreads();
  }

  const float pa = fdiv(scal[5], fmul(attnm, scal[3]));
#pragma unroll
  for (int s2 = 0; s2 < 4; s2++) {
    uint32_t pack = 0;
#pragma unroll
    for (int r = 0; r < 4; r++) {
      float t = fminf(fmaxf(fdiv((float)xacc[s2][r], pa), -4.f), 3.f);
      pack |= ((uint32_t)(uint8_t)(int8_t)rintf(t)) << (8 * r);
    }
    *(uint32_t*)&Ks[16 * w + c16][16 * s2 + 4 * quad] = pack;
  }
  __syncthreads();
  int4 ov = *(const int4*)&Ks[sr][scol];
  *(int4*)(x1q + ((size_t)bh * NN + qt * 64 + sr) * HD + scol) = ov;
}

// ---------------------------------------------------------------------------
// GEMM2 (i8 MFMA 32x32x32): barrier-free, LDS-free.  Block = 128seq x 64ch,
// wave = 32x64 (acc = 32 AGPRs).  pwq fragment-major (coalesced B loads);
// x1q keeps attn's layout (strided A loads).  launch_bounds(256,6).
// ---------------------------------------------------------------------------
__global__ __launch_bounds__(256, 6) void gemm_proj_kernel(
    const int8_t* __restrict__ x1q, const int8_t* __restrict__ Wq,
    const float* __restrict__ proj_alpha, const float* __restrict__ proj_bias,
    const float* __restrict__ scal, float* __restrict__ out) {
  const int L = blockIdx.x;
  const int xcd = L & 7, s = L >> 3;
  const int rb = xcd + 8 * (s / 12);   // 128-row slice 0..127 (XCD-resident)
  const int g = s % 12;                // column block 0..11
  const int tid = threadIdx.x;
  const int w = tid >> 6, lane = tid & 63;
  const int l31 = lane & 31, hi = lane >> 5;
  const int col0 = g * 64;
  const int b_idx = rb >> 2, nbase = (rb & 3) * 128;
  const int w32 = w * 32;

  v16i acc0 = (v16i)(0), acc1 = (v16i)(0);

  const int8_t* pa =
      x1q + ((size_t)b_idx * HH * NN + nbase + w32 + l31) * 64 + hi * 16;
  const int8_t* pb = Wq + (size_t)col0 * 64 + hi * 512 + l31 * 16;
  const size_t KTX = (size_t)NN * 64;  // head stride in x1q

#pragma unroll 1
  for (int kt = 0; kt < 12; kt++) {
    v4i Aa = *(const v4i*)(pa + kt * KTX);
    v4i Ab = *(const v4i*)(pa + kt * KTX + 32);
    v4i B0a = *(const v4i*)(pb + kt * KTP);
    v4i B0b = *(const v4i*)(pb + kt * KTP + 1024);
    v4i B1a = *(const v4i*)(pb + kt * KTP + 2048);
    v4i B1b = *(const v4i*)(pb + kt * KTP + 3072);
    acc0 = __builtin_amdgcn_mfma_i32_32x32x32_i8(B0a, Aa, acc0, 0, 0, 0);
    acc1 = __builtin_amdgcn_mfma_i32_32x32x32_i8(B1a, Aa, acc1, 0, 0, 0);
    acc0 = __builtin_amdgcn_mfma_i32_32x32x32_i8(B0b, Ab, acc0, 0, 0, 0);
    acc1 = __builtin_amdgcn_mfma_i32_32x32x32_i8(B1b, Ab, acc1, 0, 0, 0);
  }

  const float pact = scal[5];
  const int m = rb * 128 + w32 + l31;
#pragma unroll
  for (int i = 0; i < 2; i++)
#pragma unroll
    for (int b = 0; b < 4; b++) {
      int colb = col0 + 32 * i + 8 * b + 4 * hi;
      float4 al = *(const float4*)(proj_alpha + colb);
      float4 bi = *(const float4*)(proj_bias + colb);
      const float* alp = (const float*)&al;
      const float* bip = (const float*)&bi;
      float4 o;
      float* op = (float*)&o;
#pragma unroll
      for (int c = 0; c < 4; c++) {
        int av = (i == 0) ? acc0[4 * b + c] : acc1[4 * b + c];
        op[c] = fadd(fmul(fmul((float)av, alp[c]), pact), bip[c]);
      }
      *(float4*)(out + (size_t)m * CC + colb) = o;
    }
}

extern "C" void kernel_launch(void* const* d_in, const int* in_sizes, int n_in,
                              void* d_out, int out_size, void* d_ws,
                              size_t ws_size, hipStream_t stream) {
  const float* x0 = (const float*)d_in[0];
  const float* qkv_w = (const float*)d_in[1];
  const float* qkv_alpha = (const float*)d_in[2];
  const float* qkv_bias = (const float*)d_in[3];
  const float* qkv_act_alpha = (const float*)d_in[4];
  const float* proj_w = (const float*)d_in[5];
  const float* proj_alpha = (const float*)d_in[6];
  const float* proj_bias = (const float*)d_in[7];
  const float* proj_act_alpha = (const float*)d_in[8];
  const float* normq_w = (const float*)d_in[9];
  const float* normq_b = (const float*)d_in[10];
  const float* normk_w = (const float*)d_in[11];
  const float* normk_b = (const float*)d_in[12];
  const float* qact_alpha = (const float*)d_in[13];
  const float* kact_alpha = (const float*)d_in[14];
  const float* vact_alpha = (const float*)d_in[15];
  const float* attnact_alpha = (const float*)d_in[16];

  char* ws = (char*)d_ws;
  size_t off = 0;
  auto alloc = [&](size_t bytes) -> char* {
    char* p = ws + off;
    off += (bytes + 255) & ~(size_t)255;
    return p;
  };
  float* scal = (float*)alloc(64 * 4);
  float* qparams = (float*)alloc(256 * 4);
  float* biasq = (float*)alloc(QKV_C * 4);
  int8_t* x0q = (int8_t*)alloc((size_t)M_ROWS * CC);   // frag-major [12][...]
  int8_t* wq = (int8_t*)alloc((size_t)QKV_C * CC);     // frag-major [12][...]
  int8_t* pwq = (int8_t*)alloc((size_t)CC * CC);       // frag-major [12][...]
  int8_t* q2 = (int8_t*)alloc((size_t)BB * HH * NN * HD);
  int8_t* k2 = (int8_t*)alloc((size_t)BB * HH * NN * HD);
  int8_t* v2t = (int8_t*)alloc((size_t)BB * HH * NN * HD);
  int8_t* x1q = (int8_t*)alloc((size_t)M_ROWS * CC);

  prep_kernel<<<1, 256, 0, stream>>>(qkv_act_alpha, proj_act_alpha, qact_alpha,
                                     kact_alpha, vact_alpha, attnact_alpha,
                                     normq_w, normq_b, normk_w, normk_b,
                                     qkv_bias, qkv_alpha, scal, qparams, biasq);

  int total4 = M_ROWS * CC / 4;
  quant_x0_kernel<<<(total4 + 255) / 256, 256, 0, stream>>>(x0, scal, x0q,
                                                            total4);
  quant_w_kernel<<<(QKV_C * CC + 255) / 256, 256, 0, stream>>>(
      qkv_w, qkv_alpha, wq, QKV_C, QKV_C * CC);
  quant_w_kernel<<<(CC * CC + 255) / 256, 256, 0, stream>>>(
      proj_w, proj_alpha, pwq, CC, CC * CC);

  gemm_qkv_kernel<<<36 * (M_ROWS / 128), 256, 0, stream>>>(
      x0q, wq, biasq, scal, qkv_alpha, qparams, q2, k2, v2t);

  attn_kernel<<<(NN / 64) * (BB * HH), 256, 0, stream>>>(q2, k2, v2t, scal,
                                                         x1q);

  gemm_proj_kernel<<<12 * (M_ROWS / 128), 256, 0, stream>>>(
      x1q, pwq, proj_alpha, proj_bias, scal, (float*)d_out);
}